// Round 12
// baseline (724.664 us; speedup 1.0000x reference)
//
#include <hip/hip_runtime.h>
#include <hip/hip_bf16.h>
#include <math.h>

// S=4096, D=512, H=8, hd=64, F=2048, E=8, top-2. I/O fp32.
// Attention path: split-bf16 (hi+lo, 3-MFMA) emulated fp32 => fp32-faithful
// routing. MoE: sparse top-2, ALL experts in one launch, atomic fp32 scatter.
// R2: flash split-K over KV (partials + combine).
// R3: hw bf16 cvt, setprio (T5), defer-max (T13).
// R4: KP=64 + XOR 16B-granule swizzle.
// R5: in-loop reg staging (launch_bounds(256,N) caps VGPR -> spill trap).
// R6: MoE bf16 weights; split-K Wo.
// R7: swapped QK^T (S^T=mfma(K,Q)), LN2 fusion.
// R8 REVERTED: global_load_lds staging; moe_y split-K (4x atomics).
// R9: init_out folded into gate_route.
// R10: flash Q register-tiling: 32 Q rows/wave, K/V frags reused.
// R11: PV via v_mfma_f32_16x16x16_bf16: swapped-QK^T C-layout == K=16 A-frag
//      => zero cross-lane P movement. 719us, flash 158, MfmaUtil 42%.
// R12: launch-count reduction (hot kernels untouched): zero_cnt folded into
//      init_x1; make_off deleted (MoE blocks compute the 8-entry cumsum
//      locally from cnt); cvt_split_w x2 -> 1 launch; cvt_w_bf16(w1,w2) -> 1.
#define SQ   4096
#define DM   512
#define NH   8
#define HDIM 64
#define FF   2048
#define NE   8

typedef unsigned short u16;
typedef unsigned int   u32;
typedef __attribute__((ext_vector_type(8))) __bf16 bf16x8;
typedef __attribute__((ext_vector_type(4))) __bf16 bf16x4;
typedef __attribute__((ext_vector_type(4))) float  f32x4;

__device__ __forceinline__ float bf2f(u16 v) {
    union { u32 i; float f; } c; c.i = ((u32)v) << 16; return c.f;
}
// RNE via hardware cvt (v_cvt_pk_bf16_f32; same tie-to-even as manual bits)
__device__ __forceinline__ u16 f2bf(float f) {
    union { __bf16 h; u16 u; } c; c.h = (__bf16)f; return c.u;
}

// K=16 MFMA via inline asm (instruction in gfx950 ISA; builtin name varies)
__device__ __forceinline__ void mfma16(f32x4 &c, bf16x4 a, bf16x4 b) {
    asm("v_mfma_f32_16x16x16_bf16 %0, %1, %2, %0" : "+v"(c) : "v"(a), "v"(b));
}

// 128-aligned exclusive cumsum of cnt, computed locally (replaces make_off)
__device__ __forceinline__ void local_off(const int* __restrict__ cnt,
                                          int* offv)
{
    int a = 0;
#pragma unroll
    for (int e = 0; e < NE; e++) {
        offv[e] = a;
        a += ((cnt[e] + 127) >> 7) << 7;
    }
    offv[NE] = a;
}

#define BM 128
#define BN 128
#define BK 32
#define BKP 40   // padded LDS row stride for GEMM kernels

// ===========================================================================
// Split-bf16 GEMM: C = (Ahi+Alo)@(Bhi+Blo)^T + bias. 3 MFMAs (hh+hl+lh).
// mode 0: split bf16 pair out. mode 1: fp32 out (+resid).
// ===========================================================================
__global__ __launch_bounds__(256) void gemm_split(
    const u16* __restrict__ Ahi, const u16* __restrict__ Alo, int lda,
    const u16* __restrict__ Bhi, const u16* __restrict__ Blo, int ldb,
    int M, int N, int K,
    const float* __restrict__ bias,
    const float* __restrict__ resid, int ldres,
    u16* __restrict__ Chi, u16* __restrict__ Clo,
    float* __restrict__ Cf, int ldc, int mode)
{
    __shared__ __align__(16) u16 Ash[BM * BKP], Asl[BM * BKP];
    __shared__ __align__(16) u16 Bsh[BN * BKP], Bsl[BN * BKP];
    const int tid  = threadIdx.x;
    const int wave = tid >> 6;
    const int lane = tid & 63;
    const int quad = lane >> 4;
    const int l16  = lane & 15;
    const int bm = blockIdx.x * BM;
    const int bn = blockIdx.y * BN;
    const int wm = (wave & 1) * 64;
    const int wn = (wave >> 1) * 64;

    f32x4 acc[4][4];
#pragma unroll
    for (int i = 0; i < 4; i++)
#pragma unroll
        for (int j = 0; j < 4; j++)
#pragma unroll
            for (int r = 0; r < 4; r++) acc[i][j][r] = 0.0f;

    for (int k0 = 0; k0 < K; k0 += BK) {
#pragma unroll
        for (int i = 0; i < 2; i++) {
            int c = tid + i * 256;
            int row = c >> 2;
            int col = (c & 3) << 3;
            int ga = bm + row, gb2 = bn + row;
            uint4 vah = make_uint4(0u,0u,0u,0u), val = vah, vbh = vah, vbl = vah;
            if (ga < M) {
                vah = *(const uint4*)(Ahi + (size_t)ga * lda + k0 + col);
                val = *(const uint4*)(Alo + (size_t)ga * lda + k0 + col);
            }
            if (gb2 < N) {
                vbh = *(const uint4*)(Bhi + (size_t)gb2 * ldb + k0 + col);
                vbl = *(const uint4*)(Blo + (size_t)gb2 * ldb + k0 + col);
            }
            *(uint4*)(Ash + row * BKP + col) = vah;
            *(uint4*)(Asl + row * BKP + col) = val;
            *(uint4*)(Bsh + row * BKP + col) = vbh;
            *(uint4*)(Bsl + row * BKP + col) = vbl;
        }
        __syncthreads();
        bf16x8 ah[4], al[4], bh[4], bl[4];
#pragma unroll
        for (int i = 0; i < 4; i++) {
            ah[i] = *(const bf16x8*)(Ash + (wm + i * 16 + l16) * BKP + quad * 8);
            al[i] = *(const bf16x8*)(Asl + (wm + i * 16 + l16) * BKP + quad * 8);
        }
#pragma unroll
        for (int j = 0; j < 4; j++) {
            bh[j] = *(const bf16x8*)(Bsh + (wn + j * 16 + l16) * BKP + quad * 8);
            bl[j] = *(const bf16x8*)(Bsl + (wn + j * 16 + l16) * BKP + quad * 8);
        }
#pragma unroll
        for (int i = 0; i < 4; i++)
#pragma unroll
            for (int j = 0; j < 4; j++) {
                acc[i][j] = __builtin_amdgcn_mfma_f32_16x16x32_bf16(ah[i], bh[j], acc[i][j], 0,0,0);
                acc[i][j] = __builtin_amdgcn_mfma_f32_16x16x32_bf16(ah[i], bl[j], acc[i][j], 0,0,0);
                acc[i][j] = __builtin_amdgcn_mfma_f32_16x16x32_bf16(al[i], bh[j], acc[i][j], 0,0,0);
            }
        __syncthreads();
    }

#pragma unroll
    for (int i = 0; i < 4; i++)
#pragma unroll
        for (int j = 0; j < 4; j++)
#pragma unroll
            for (int r = 0; r < 4; r++) {
                int row = bm + wm + i * 16 + quad * 4 + r;
                int col = bn + wn + j * 16 + l16;
                if (row >= M || col >= N) continue;
                float v = acc[i][j][r] + (bias ? bias[col] : 0.0f);
                size_t idx = (size_t)row * ldc + col;
                if (mode == 0) {
                    u16 hb = f2bf(v);
                    Chi[idx] = hb;
                    Clo[idx] = f2bf(v - bf2f(hb));
                } else {
                    if (resid) v += resid[(size_t)row * ldres + col];
                    Cf[idx] = v;
                }
            }
}

// ===========================================================================
// Split-K Wo projection: x1 += partial[(Ahi+Alo)@(Bhi+Blo)^T] over K-chunk z.
// grid (32, 4, 4). x1 must be pre-initialized with src + bias (init_x1).
// ===========================================================================
__global__ __launch_bounds__(256) void gemm_split_ko(
    const u16* __restrict__ Ahi, const u16* __restrict__ Alo, int lda,
    const u16* __restrict__ Bhi, const u16* __restrict__ Blo, int ldb,
    float* __restrict__ Cf, int ldc)
{
    __shared__ __align__(16) u16 Ash[BM * BKP], Asl[BM * BKP];
    __shared__ __align__(16) u16 Bsh[BN * BKP], Bsl[BN * BKP];
    const int tid  = threadIdx.x;
    const int wave = tid >> 6;
    const int lane = tid & 63;
    const int quad = lane >> 4;
    const int l16  = lane & 15;
    const int bm = blockIdx.x * BM;
    const int bn = blockIdx.y * BN;
    const int wm = (wave & 1) * 64;
    const int wn = (wave >> 1) * 64;
    const int KC    = DM / 4;              // 128 per z-chunk
    const int k0beg = blockIdx.z * KC;

    f32x4 acc[4][4];
#pragma unroll
    for (int i = 0; i < 4; i++)
#pragma unroll
        for (int j = 0; j < 4; j++)
#pragma unroll
            for (int r = 0; r < 4; r++) acc[i][j][r] = 0.0f;

    for (int k0 = k0beg; k0 < k0beg + KC; k0 += BK) {
#pragma unroll
        for (int i = 0; i < 2; i++) {
            int c = tid + i * 256;
            int row = c >> 2;
            int col = (c & 3) << 3;
            int ga = bm + row, gb2 = bn + row;
            uint4 vah = *(const uint4*)(Ahi + (size_t)ga * lda + k0 + col);
            uint4 val = *(const uint4*)(Alo + (size_t)ga * lda + k0 + col);
            uint4 vbh = *(const uint4*)(Bhi + (size_t)gb2 * ldb + k0 + col);
            uint4 vbl = *(const uint4*)(Blo + (size_t)gb2 * ldb + k0 + col);
            *(uint4*)(Ash + row * BKP + col) = vah;
            *(uint4*)(Asl + row * BKP + col) = val;
            *(uint4*)(Bsh + row * BKP + col) = vbh;
            *(uint4*)(Bsl + row * BKP + col) = vbl;
        }
        __syncthreads();
        bf16x8 ah[4], al[4], bh[4], bl[4];
#pragma unroll
        for (int i = 0; i < 4; i++) {
            ah[i] = *(const bf16x8*)(Ash + (wm + i * 16 + l16) * BKP + quad * 8);
            al[i] = *(const bf16x8*)(Asl + (wm + i * 16 + l16) * BKP + quad * 8);
        }
#pragma unroll
        for (int j = 0; j < 4; j++) {
            bh[j] = *(const bf16x8*)(Bsh + (wn + j * 16 + l16) * BKP + quad * 8);
            bl[j] = *(const bf16x8*)(Bsl + (wn + j * 16 + l16) * BKP + quad * 8);
        }
#pragma unroll
        for (int i = 0; i < 4; i++)
#pragma unroll
            for (int j = 0; j < 4; j++) {
                acc[i][j] = __builtin_amdgcn_mfma_f32_16x16x32_bf16(ah[i], bh[j], acc[i][j], 0,0,0);
                acc[i][j] = __builtin_amdgcn_mfma_f32_16x16x32_bf16(ah[i], bl[j], acc[i][j], 0,0,0);
                acc[i][j] = __builtin_amdgcn_mfma_f32_16x16x32_bf16(al[i], bh[j], acc[i][j], 0,0,0);
            }
        __syncthreads();
    }

#pragma unroll
    for (int i = 0; i < 4; i++)
#pragma unroll
        for (int j = 0; j < 4; j++)
#pragma unroll
            for (int r = 0; r < 4; r++) {
                int row = bm + wm + i * 16 + quad * 4 + r;
                int col = bn + wn + j * 16 + l16;
                atomicAdd(Cf + (size_t)row * ldc + col, acc[i][j][r]);
            }
}

// x1 = src + out_proj bias; also zeroes the MoE route counters (was zero_cnt)
__global__ __launch_bounds__(256) void init_x1(
    const float* __restrict__ src, const float* __restrict__ bias,
    float* __restrict__ x1, int* __restrict__ cnt)
{
    int i = blockIdx.x * 256 + threadIdx.x;      // float4 index
    if (blockIdx.x == 0 && threadIdx.x < NE) cnt[threadIdx.x] = 0;
    int col4 = i & (DM / 4 - 1);
    float4 s = ((const float4*)src)[i];
    float4 b = ((const float4*)bias)[col4];
    s.x += b.x; s.y += b.y; s.z += b.z; s.w += b.w;
    ((float4*)x1)[i] = s;
}

// ===========================================================================
// MoE all-expert fused w1/w2 GEMM (fp32-weight fallback path)
// ===========================================================================
__global__ __launch_bounds__(256) void moe12_all(
    const u16* __restrict__ A, int lda,
    const int* __restrict__ idxl, const int* __restrict__ cnt,
    const float* __restrict__ w1, const float* __restrict__ b1,
    const float* __restrict__ w2, const float* __restrict__ b2,
    u16* __restrict__ H)
{
    int offv[NE + 1];
    local_off(cnt, offv);
    const int bmg = blockIdx.x * BM;
    if (bmg >= offv[NE]) return;
    int e = 0;
    while (e < NE - 1 && bmg >= offv[e + 1]) e++;
    const int M   = cnt[e];
    const int bml = bmg - offv[e];
    if (bml >= M) return;
    const float* B1 = w1 + (size_t)e * FF * DM;
    const float* B2 = w2 + (size_t)e * FF * DM;
    const int*   rl = idxl + e * SQ;

    __shared__ __align__(16) u16 As[BM * BKP], Bs1[BN * BKP], Bs2[BN * BKP];
    const int tid  = threadIdx.x;
    const int wave = tid >> 6;
    const int lane = tid & 63;
    const int quad = lane >> 4;
    const int l16  = lane & 15;
    const int bn = blockIdx.y * BN;
    const int wm = (wave & 1) * 64;
    const int wn = (wave >> 1) * 64;

    f32x4 acc1[4][4], acc2[4][4];
#pragma unroll
    for (int i = 0; i < 4; i++)
#pragma unroll
        for (int j = 0; j < 4; j++)
#pragma unroll
            for (int r = 0; r < 4; r++) { acc1[i][j][r] = 0.0f; acc2[i][j][r] = 0.0f; }

    for (int k0 = 0; k0 < DM; k0 += BK) {
#pragma unroll
        for (int i = 0; i < 2; i++) {
            int c = tid + i * 256;
            int row = c >> 2;
            int col = (c & 3) << 3;
            uint4 va = make_uint4(0u,0u,0u,0u);
            int lr = bml + row;
            if (lr < M) {
                int ar = rl[lr];
                va = *(const uint4*)(A + (size_t)ar * lda + k0 + col);
            }
            *(uint4*)(As + row * BKP + col) = va;
        }
#pragma unroll
        for (int i = 0; i < 4; i++) {
            int c = tid + i * 256;
            int row = c >> 3;
            int col = (c & 7) << 2;
            float4 v1 = *(const float4*)(B1 + (size_t)(bn + row) * DM + k0 + col);
            float4 v2 = *(const float4*)(B2 + (size_t)(bn + row) * DM + k0 + col);
            ushort4 h1, h2;
            h1.x = f2bf(v1.x); h1.y = f2bf(v1.y); h1.z = f2bf(v1.z); h1.w = f2bf(v1.w);
            h2.x = f2bf(v2.x); h2.y = f2bf(v2.y); h2.z = f2bf(v2.z); h2.w = f2bf(v2.w);
            *(ushort4*)(Bs1 + row * BKP + col) = h1;
            *(ushort4*)(Bs2 + row * BKP + col) = h2;
        }
        __syncthreads();
        bf16x8 af[4], b1f[4], b2f[4];
#pragma unroll
        for (int i = 0; i < 4; i++)
            af[i] = *(const bf16x8*)(As + (wm + i * 16 + l16) * BKP + quad * 8);
#pragma unroll
        for (int j = 0; j < 4; j++) {
            b1f[j] = *(const bf16x8*)(Bs1 + (wn + j * 16 + l16) * BKP + quad * 8);
            b2f[j] = *(const bf16x8*)(Bs2 + (wn + j * 16 + l16) * BKP + quad * 8);
        }
#pragma unroll
        for (int i = 0; i < 4; i++)
#pragma unroll
            for (int j = 0; j < 4; j++) {
                acc1[i][j] = __builtin_amdgcn_mfma_f32_16x16x32_bf16(af[i], b1f[j], acc1[i][j], 0,0,0);
                acc2[i][j] = __builtin_amdgcn_mfma_f32_16x16x32_bf16(af[i], b2f[j], acc2[i][j], 0,0,0);
            }
        __syncthreads();
    }

#pragma unroll
    for (int i = 0; i < 4; i++)
#pragma unroll
        for (int j = 0; j < 4; j++)
#pragma unroll
            for (int r = 0; r < 4; r++) {
                int rowl = bml + wm + i * 16 + quad * 4 + r;
                if (rowl >= M) continue;
                int col = bn + wn + j * 16 + l16;
                float g1 = acc1[i][j][r] + b1[e * FF + col];
                float g2 = acc2[i][j][r] + b2[e * FF + col];
                float s  = g1 / (1.0f + __expf(-g1));
                H[(size_t)(offv[e] + rowl) * FF + col] = f2bf(s * g2);
            }
}

// ===========================================================================
// MoE fused w1/w2 GEMM, pre-converted bf16 weights (identical numerics).
// ===========================================================================
__global__ __launch_bounds__(256) void moe12_bf16(
    const u16* __restrict__ A, int lda,
    const int* __restrict__ idxl, const int* __restrict__ cnt,
    const u16* __restrict__ w1b, const float* __restrict__ b1,
    const u16* __restrict__ w2b, const float* __restrict__ b2,
    u16* __restrict__ H)
{
    int offv[NE + 1];
    local_off(cnt, offv);
    const int bmg = blockIdx.x * BM;
    if (bmg >= offv[NE]) return;
    int e = 0;
    while (e < NE - 1 && bmg >= offv[e + 1]) e++;
    const int M   = cnt[e];
    const int bml = bmg - offv[e];
    if (bml >= M) return;
    const u16* B1 = w1b + (size_t)e * FF * DM;
    const u16* B2 = w2b + (size_t)e * FF * DM;
    const int* rl = idxl + e * SQ;

    __shared__ __align__(16) u16 As[BM * BKP], Bs1[BN * BKP], Bs2[BN * BKP];
    const int tid  = threadIdx.x;
    const int wave = tid >> 6;
    const int lane = tid & 63;
    const int quad = lane >> 4;
    const int l16  = lane & 15;
    const int bn = blockIdx.y * BN;
    const int wm = (wave & 1) * 64;
    const int wn = (wave >> 1) * 64;

    f32x4 acc1[4][4], acc2[4][4];
#pragma unroll
    for (int i = 0; i < 4; i++)
#pragma unroll
        for (int j = 0; j < 4; j++)
#pragma unroll
            for (int r = 0; r < 4; r++) { acc1[i][j][r] = 0.0f; acc2[i][j][r] = 0.0f; }

    for (int k0 = 0; k0 < DM; k0 += BK) {
#pragma unroll
        for (int i = 0; i < 2; i++) {
            int c = tid + i * 256;
            int row = c >> 2;
            int col = (c & 3) << 3;
            uint4 va = make_uint4(0u,0u,0u,0u);
            int lr = bml + row;
            if (lr < M) {
                int ar = rl[lr];
                va = *(const uint4*)(A + (size_t)ar * lda + k0 + col);
            }
            *(uint4*)(As + row * BKP + col) = va;
            uint4 v1 = *(const uint4*)(B1 + (size_t)(bn + row) * DM + k0 + col);
            uint4 v2 = *(const uint4*)(B2 + (size_t)(bn + row) * DM + k0 + col);
            *(uint4*)(Bs1 + row * BKP + col) = v1;
            *(uint4*)(Bs2 + row * BKP + col) = v2;
        }
        __syncthreads();
        bf16x8 af[4], b1f[4], b2f[4];
#pragma unroll
        for (int i = 0; i < 4; i++)
            af[i] = *(const bf16x8*)(As + (wm + i * 16 + l16) * BKP + quad * 8);
#pragma unroll
        for (int j = 0; j < 4; j++) {
            b1f[j] = *(const bf16x8*)(Bs1 + (wn + j * 16 + l16) * BKP + quad * 8);
            b2f[j] = *(const bf16x8*)(Bs2 + (wn + j * 16 + l16) * BKP + quad * 8);
        }
#pragma unroll
        for (int i = 0; i < 4; i++)
#pragma unroll
            for (int j = 0; j < 4; j++) {
                acc1[i][j] = __builtin_amdgcn_mfma_f32_16x16x32_bf16(af[i], b1f[j], acc1[i][j], 0,0,0);
                acc2[i][j] = __builtin_amdgcn_mfma_f32_16x16x32_bf16(af[i], b2f[j], acc2[i][j], 0,0,0);
            }
        __syncthreads();
    }

#pragma unroll
    for (int i = 0; i < 4; i++)
#pragma unroll
        for (int j = 0; j < 4; j++)
#pragma unroll
            for (int r = 0; r < 4; r++) {
                int rowl = bml + wm + i * 16 + quad * 4 + r;
                if (rowl >= M) continue;
                int col = bn + wn + j * 16 + l16;
                float g1 = acc1[i][j][r] + b1[e * FF + col];
                float g2 = acc2[i][j][r] + b2[e * FF + col];
                float s  = g1 / (1.0f + __expf(-g1));
                H[(size_t)(offv[e] + rowl) * FF + col] = f2bf(s * g2);
            }
}

// ===========================================================================
// MoE down-proj (fp32-weight fallback path), grid (72,4)
// ===========================================================================
__global__ __launch_bounds__(256) void moe_y_all(
    const u16* __restrict__ H,
    const float* __restrict__ wo, const float* __restrict__ bo,
    const int* __restrict__ idxl, const float* __restrict__ cw,
    const int* __restrict__ cnt,
    float* __restrict__ out)
{
    int offv[NE + 1];
    local_off(cnt, offv);
    const int bmg = blockIdx.x * BM;
    if (bmg >= offv[NE]) return;
    int e = 0;
    while (e < NE - 1 && bmg >= offv[e + 1]) e++;
    const int M   = cnt[e];
    const int bml = bmg - offv[e];
    if (bml >= M) return;
    const float* B = wo + (size_t)e * DM * FF;

    __shared__ __align__(16) u16 As[BM * BKP], Bs[BN * BKP];
    const int tid  = threadIdx.x;
    const int wave = tid >> 6;
    const int lane = tid & 63;
    const int quad = lane >> 4;
    const int l16  = lane & 15;
    const int bn = blockIdx.y * BN;
    const int wm = (wave & 1) * 64;
    const int wn = (wave >> 1) * 64;

    f32x4 acc[4][4];
#pragma unroll
    for (int i = 0; i < 4; i++)
#pragma unroll
        for (int j = 0; j < 4; j++)
#pragma unroll
            for (int r = 0; r < 4; r++) acc[i][j][r] = 0.0f;

    for (int k0 = 0; k0 < FF; k0 += BK) {
#pragma unroll
        for (int i = 0; i < 2; i++) {
            int c = tid + i * 256;
            int row = c >> 2;
            int col = (c & 3) << 3;
            uint4 va = *(const uint4*)(H + (size_t)(bmg + row) * FF + k0 + col);
            *(uint4*)(As + row * BKP + col) = va;
        }
#pragma unroll
        for (int i = 0; i < 4; i++) {
            int c = tid + i * 256;
            int row = c >> 3;
            int col = (c & 7) << 2;
            float4 v = *(const float4*)(B + (size_t)(bn + row) * FF + k0 + col);
            ushort4 h;
            h.x = f2bf(v.x); h.y = f2bf(v.y); h.z = f2bf(v.z); h.w = f2bf(v.w);
            *(ushort4*)(Bs + row * BKP + col) = h;
        }
        __syncthreads();
        bf16x8 af[4], bf[4];
#pragma unroll
        for (int i = 0; i < 4; i++)
            af[i] = *(const bf16x8*)(As + (wm + i * 16 + l16) * BKP + quad * 8);
#pragma unroll
        for (int j = 0; j < 4; j++)
            bf[j] = *(const bf16x8*)(Bs + (wn + j * 16 + l16) * BKP + quad * 8);
#pragma unroll
        for (int i = 0; i < 4; i++)
#pragma unroll
            for (int j = 0; j < 4; j++)
                acc[i][j] = __builtin_amdgcn_mfma_f32_16x16x32_bf16(af[i], bf[j], acc[i][j], 0,0,0);
        __syncthreads();
    }

#pragma unroll
    for (int i = 0; i < 4; i++)
#pragma unroll
        for (int j = 0; j < 4; j++)
#pragma unroll
            for (int r = 0; r < 4; r++) {
                int rowl = bml + wm + i * 16 + quad * 4 + r;
                if (rowl >= M) continue;
                int col = bn + wn + j * 16 + l16;
                int tok = idxl[e * SQ + rowl];
                float wgt = cw[e * SQ + rowl];
                atomicAdd(out + (size_t)tok * DM + col,
                          wgt * (acc[i][j][r] + bo[e * DM + col]));
            }
}

// ===========================================================================
// MoE down-proj, pre-converted bf16 wo (identical numerics), grid (72,4)
// ===========================================================================
__global__ __launch_bounds__(256) void moe_y_bf16(
    const u16* __restrict__ H,
    const u16* __restrict__ wob, const float* __restrict__ bo,
    const int* __restrict__ idxl, const float* __restrict__ cw,
    const int* __restrict__ cnt,
    float* __restrict__ out)
{
    int offv[NE + 1];
    local_off(cnt, offv);
    const int bmg = blockIdx.x * BM;
    if (bmg >= offv[NE]) return;
    int e = 0;
    while (e < NE - 1 && bmg >= offv[e + 1]) e++;
    const int M   = cnt[e];
    const int bml = bmg - offv[e];
    if (bml >= M) return;
    const u16* B = wob + (size_t)e * DM * FF;

    __shared__ __align__(16) u16 As[BM * BKP], Bs[BN * BKP];
    const int tid  = threadIdx.x;
    const int wave = tid >> 6;
    const int lane = tid & 63;
    const int quad = lane >> 4;
    const int l16  = lane & 15;
    const int bn = blockIdx.y * BN;
    const int wm = (wave & 1) * 64;
    const int wn = (wave >> 1) * 64;

    f32x4 acc[4][4];
#pragma unroll
    for (int i = 0; i < 4; i++)
#pragma unroll
        for (int j = 0; j < 4; j++)
#pragma unroll
            for (int r = 0; r < 4; r++) acc[i][j][r] = 0.0f;

    for (int k0 = 0; k0 < FF; k0 += BK) {
#pragma unroll
        for (int i = 0; i < 2; i++) {
            int c = tid + i * 256;
            int row = c >> 2;
            int col = (c & 3) << 3;
            uint4 va = *(const uint4*)(H + (size_t)(bmg + row) * FF + k0 + col);
            *(uint4*)(As + row * BKP + col) = va;
            uint4 vb = *(const uint4*)(B + (size_t)(bn + row) * FF + k0 + col);
            *(uint4*)(Bs + row * BKP + col) = vb;
        }
        __syncthreads();
        bf16x8 af[4], bf[4];
#pragma unroll
        for (int i = 0; i < 4; i++)
            af[i] = *(const bf16x8*)(As + (wm + i * 16 + l16) * BKP + quad * 8);
#pragma unroll
        for (int j = 0; j < 4; j++)
            bf[j] = *(const bf16x8*)(Bs + (wn + j * 16 + l16) * BKP + quad * 8);
#pragma unroll
        for (int i = 0; i < 4; i++)
#pragma unroll
            for (int j = 0; j < 4; j++)
                acc[i][j] = __builtin_amdgcn_mfma_f32_16x16x32_bf16(af[i], bf[j], acc[i][j], 0,0,0);
        __syncthreads();
    }

#pragma unroll
    for (int i = 0; i < 4; i++)
#pragma unroll
        for (int j = 0; j < 4; j++)
#pragma unroll
            for (int r = 0; r < 4; r++) {
                int rowl = bml + wm + i * 16 + quad * 4 + r;
                if (rowl >= M) continue;
                int col = bn + wn + j * 16 + l16;
                int tok = idxl[e * SQ + rowl];
                float wgt = cw[e * SQ + rowl];
                atomicAdd(out + (size_t)tok * DM + col,
                          wgt * (acc[i][j][r] + bo[e * DM + col]));
            }
}

// fp32 -> bf16 (RNE), float4/ushort4, TWO tensors in one launch
__global__ __launch_bounds__(256) void cvt_w_bf16_2(
    const float* __restrict__ wa, u16* __restrict__ wba,
    const float* __restrict__ wb, u16* __restrict__ wbb, int n4)
{
    int i = blockIdx.x * 256 + threadIdx.x;
    const float* w; u16* o; int idx;
    if (i < n4) { w = wa; o = wba; idx = i; }
    else        { w = wb; o = wbb; idx = i - n4; }
    float4 v = ((const float4*)w)[idx];
    ushort4 h;
    h.x = f2bf(v.x); h.y = f2bf(v.y); h.z = f2bf(v.z); h.w = f2bf(v.w);
    ((ushort4*)o)[idx] = h;
}

// fp32 -> bf16, single tensor
__global__ __launch_bounds__(256) void cvt_w_bf16(
    const float* __restrict__ w, u16* __restrict__ wb, int n4)
{
    int i = blockIdx.x * 256 + threadIdx.x;
    if (i < n4) {
        float4 v = ((const float4*)w)[i];
        ushort4 h;
        h.x = f2bf(v.x); h.y = f2bf(v.y); h.z = f2bf(v.z); h.w = f2bf(v.w);
        ((ushort4*)wb)[i] = h;
    }
}

// ===========================================================================
// Flash attention, split precision, SWAPPED QK^T (S^T = mfma(K, Q)).
// R10: each wave owns TWO 16-row Q blocks (qb=0,1); K/V frags reused.
// R11: PV via K=16 MFMAs (C-layout == A-frag layout; lane-local P).
// LDS: KP=64, XOR 16B-granule swizzle. SPLIT in {1,2,4} over KV.
// ===========================================================================
#define KP 64
#define SWZ(row, col) ((col) ^ (((row) & 7) << 3))   // u16 units, 16B granules
#define SCL 0.18033688011112042f   // 0.125 * log2(e)

// softmax + defer-max + bf16 split pack (lane-local, K=16 A-frags).
__device__ __forceinline__ void smax_pack(
    f32x4 (&s)[4], float &m_, float &l_, f32x4 (&o_)[4],
    bf16x4 (&pah)[4], bf16x4 (&pal)[4], int quad)
{
    // row max: local over 16 regs + 2 cross-quad shfl_xor
    float mx = s[0][0];
#pragma unroll
    for (int jn = 0; jn < 4; jn++)
#pragma unroll
        for (int r = 0; r < 4; r++) mx = fmaxf(mx, s[jn][r]);
    mx = fmaxf(mx, __shfl_xor(mx, 16));
    mx = fmaxf(mx, __shfl_xor(mx, 32));

    // defer-max (T13): only rescale when the max grew by >8 (p <= 2^8)
    int grew = (mx > m_ + 8.0f) ? 1 : 0;
    if (__any(grew)) {
        float nm  = fmaxf(m_, mx);
        float al2 = exp2f(m_ - nm);
        m_ = nm;
        l_ *= al2;
        float alq[4];
#pragma unroll
        for (int r = 0; r < 4; r++)
            alq[r] = __shfl(al2, quad*4 + r);   // al2 for q = quad*4+r
#pragma unroll
        for (int nd = 0; nd < 4; nd++)
#pragma unroll
            for (int r = 0; r < 4; r++) o_[nd][r] *= alq[r];
    }

    // p = exp2(s - m), row sum: local + 2 shfl_xor
    float rs = 0.0f;
#pragma unroll
    for (int jn = 0; jn < 4; jn++)
#pragma unroll
        for (int r = 0; r < 4; r++) {
            float p = exp2f(s[jn][r] - m_);
            s[jn][r] = p;
            rs += p;
        }
    rs += __shfl_xor(rs, 16);
    rs += __shfl_xor(rs, 32);
    l_ += rs;

    // pack hi/lo K=16 A-frags: reg j = P[q=l16][k=jn*16+quad*4+j] (lane-local)
#pragma unroll
    for (int jn = 0; jn < 4; jn++) {
        union { bf16x4 v; u16 u[4]; } hh, ll;
#pragma unroll
        for (int j = 0; j < 4; j++) {
            u16 hb = f2bf(s[jn][j]);
            hh.u[j] = hb;
            ll.u[j] = f2bf(s[jn][j] - bf2f(hb));
        }
        pah[jn] = hh.v;
        pal[jn] = ll.v;
    }
}

template <int SPLIT>
__device__ __forceinline__ void flash_body(
    const u16* __restrict__ qh, const u16* __restrict__ ql,
    const u16* __restrict__ vth, const u16* __restrict__ vtl,
    u16* __restrict__ oh, u16* __restrict__ ol,
    float* __restrict__ Opart, float* __restrict__ mpart,
    float* __restrict__ lpart)
{
    __shared__ __align__(16) u16 Ksh[64*KP], Ksl[64*KP], Vsh[64*KP], Vsl[64*KP];
    const int tid  = threadIdx.x;
    const int wave = tid >> 6;
    const int lane = tid & 63;
    const int quad = lane >> 4;
    const int l16  = lane & 15;
    const int h    = blockIdx.y;
    const int z    = (SPLIT > 1) ? blockIdx.z : 0;
    const int qbase = blockIdx.x * 128 + wave * 32;   // 32 Q rows per wave

    // staging geometry: thread covers rows (tid>>3) and (tid>>3)+32, 8 u16 cols
    const int r_st  = tid >> 3;                    // 0..31
    const int co_g  = (tid & 7) << 3;              // global col (u16)
    const int co_sw = SWZ(r_st, co_g);             // same for r_st+32 (&7 inv)

    // Q fragments for both 16-row blocks
    bf16x8 aqh0[2], aql0[2], aqh1[2], aql1[2];
#pragma unroll
    for (int kk = 0; kk < 2; kk++) {
        size_t off0 = (size_t)(qbase + l16) * (3*DM) + h*HDIM + kk*32 + quad*8;
        size_t off1 = off0 + (size_t)16 * (3*DM);
        aqh0[kk] = *(const bf16x8*)(qh + off0);
        aql0[kk] = *(const bf16x8*)(ql + off0);
        aqh1[kk] = *(const bf16x8*)(qh + off1);
        aql1[kk] = *(const bf16x8*)(ql + off1);
    }

    float m0 = -1e30f, l0 = 0.0f, m1 = -1e30f, l1 = 0.0f;
    f32x4 o0[4], o1[4];
#pragma unroll
    for (int nd = 0; nd < 4; nd++)
#pragma unroll
        for (int r = 0; r < 4; r++) { o0[nd][r] = 0.0f; o1[nd][r] = 0.0f; }

    const int NT    = SQ / 64 / SPLIT;
    const int jtBeg = z * NT, jtEnd = (z + 1) * NT;

    for (int jt = jtBeg; jt < jtEnd; jt++) {
        // stage K/V tile: global -> reg -> LDS (swizzled dest), in-loop
        {
            size_t koff0 = (size_t)(jt*64 + r_st) * (3*DM) + DM + h*HDIM + co_g;
            size_t voff0 = (size_t)(h*HDIM + r_st) * SQ + jt*64 + co_g;
            size_t koff1 = koff0 + (size_t)32 * (3*DM);
            size_t voff1 = voff0 + (size_t)32 * SQ;
            uint4 a0 = *(const uint4*)(qh  + koff0);
            uint4 a1 = *(const uint4*)(ql  + koff0);
            uint4 a2 = *(const uint4*)(vth + voff0);
            uint4 a3 = *(const uint4*)(vtl + voff0);
            uint4 b0 = *(const uint4*)(qh  + koff1);
            uint4 b1 = *(const uint4*)(ql  + koff1);
            uint4 b2 = *(const uint4*)(vth + voff1);
            uint4 b3 = *(const uint4*)(vtl + voff1);
            *(uint4*)(Ksh + r_st*KP + co_sw)      = a0;
            *(uint4*)(Ksl + r_st*KP + co_sw)      = a1;
            *(uint4*)(Vsh + r_st*KP + co_sw)      = a2;
            *(uint4*)(Vsl + r_st*KP + co_sw)      = a3;
            *(uint4*)(Ksh + (r_st+32)*KP + co_sw) = b0;
            *(uint4*)(Ksl + (r_st+32)*KP + co_sw) = b1;
            *(uint4*)(Vsh + (r_st+32)*KP + co_sw) = b2;
            *(uint4*)(Vsl + (r_st+32)*KP + co_sw) = b3;
        }
        __syncthreads();

        // QK^T swapped for both qb; K frags loaded ONCE, used 6x.
        f32x4 s0[4], s1[4];
        __builtin_amdgcn_s_setprio(1);
#pragma unroll
        for (int jn = 0; jn < 4; jn++) {
            f32x4 z0, z1;
#pragma unroll
            for (int r = 0; r < 4; r++) { z0[r] = 0.0f; z1[r] = 0.0f; }
#pragma unroll
            for (int kk = 0; kk < 2; kk++) {
                int krow = jn*16 + l16;
                int kcol = SWZ(krow, kk*32 + quad*8);
                bf16x8 kh = *(const bf16x8*)(Ksh + krow*KP + kcol);
                bf16x8 kl = *(const bf16x8*)(Ksl + krow*KP + kcol);
                z0 = __builtin_amdgcn_mfma_f32_16x16x32_bf16(kh, aqh0[kk], z0, 0,0,0);
                z0 = __builtin_amdgcn_mfma_f32_16x16x32_bf16(kl, aqh0[kk], z0, 0,0,0);
                z0 = __builtin_amdgcn_mfma_f32_16x16x32_bf16(kh, aql0[kk], z0, 0,0,0);
                z1 = __builtin_amdgcn_mfma_f32_16x16x32_bf16(kh, aqh1[kk], z1, 0,0,0);
                z1 = __builtin_amdgcn_mfma_f32_16x16x32_bf16(kl, aqh1[kk], z1, 0,0,0);
                z1 = __builtin_amdgcn_mfma_f32_16x16x32_bf16(kh, aql1[kk], z1, 0,0,0);
            }
#pragma unroll
            for (int r = 0; r < 4; r++) { z0[r] *= SCL; z1[r] *= SCL; }
            s0[jn] = z0;
            s1[jn] = z1;
        }
        __builtin_amdgcn_s_setprio(0);

        // softmax + lane-local pack per qb (no cross-lane redistribution)
        bf16x4 pah0[4], pal0[4], pah1[4], pal1[4];
        smax_pack(s0, m0, l0, o0, pah0, pal0, quad);
        smax_pack(s1, m1, l1, o1, pah1, pal1, quad);

        // PV via K=16 MFMAs; V b64 frags loaded ONCE, used 6x.
        __builtin_amdgcn_s_setprio(1);
#pragma unroll
        for (int nd = 0; nd < 4; nd++) {
            int vrow = nd*16 + l16;
#pragma unroll
            for (int jn = 0; jn < 4; jn++) {
                int vcol = SWZ(vrow, jn*16 + quad*4);
                bf16x4 vh = *(const bf16x4*)(Vsh + vrow*KP + vcol);
                bf16x4 vl = *(const bf16x4*)(Vsl + vrow*KP + vcol);
                mfma16(o0[nd], pah0[jn], vh);
                mfma16(o0[nd], pah0[jn], vl);
                mfma16(o0[nd], pal0[jn], vh);
                mfma16(o1[nd], pah1[jn], vh);
                mfma16(o1[nd], pah1[jn], vl);
                mfma16(o1[nd], pal1[jn], vh);
            }
        }
        __builtin_amdgcn_s_setprio(0);
        __syncthreads();   // before next tile overwrites Ks/Vs
    }

    if (SPLIT == 1) {
        float lq0[4], lq1[4];
#pragma unroll
        for (int r = 0; r < 4; r++) {
            lq0[r] = __shfl(l0, quad*4 + r);
            lq1[r] = __shfl(l1, quad*4 + r);
        }
#pragma unroll
        for (int nd = 0; nd < 4; nd++)
#pragma unroll
            for (int r = 0; r < 4; r++) {
                int row = qbase + quad*4 + r;
                int col = h*HDIM + nd*16 + l16;
                float w = o0[nd][r] / lq0[r];
                u16 hb = f2bf(w);
                oh[(size_t)row * DM + col] = hb;
                ol[(size_t)row * DM + col] = f2bf(w - bf2f(hb));
                int row1 = row + 16;
                float w1v = o1[nd][r] / lq1[r];
                u16 hb1 = f2bf(w1v);
                oh[(size_t)row1 * DM + col] = hb1;
                ol[(size_t)row1 * DM + col] = f2bf(w1v - bf2f(hb1));
            }
    } else {
        // unnormalized fp32 partials + per-row m/l (lanes 0..15 own q=l16)
#pragma unroll
        for (int nd = 0; nd < 4; nd++)
#pragma unroll
            for (int r = 0; r < 4; r++) {
                int row = qbase + quad*4 + r;
                int col = h*HDIM + nd*16 + l16;
                Opart[((size_t)z * SQ + row) * DM + col] = o0[nd][r];
                Opart[((size_t)z * SQ + row + 16) * DM + col] = o1[nd][r];
            }
        if (lane < 16) {
            int row = qbase + l16;
            mpart[(z*NH + h) * SQ + row] = m0;
            lpart[(z*NH + h) * SQ + row] = l0;
            mpart[(z*NH + h) * SQ + row + 16] = m1;
            lpart[(z*NH + h) * SQ + row + 16] = l1;
        }
    }
}

__global__ __launch_bounds__(256) void flash_attn(
    const u16* __restrict__ qh, const u16* __restrict__ ql,
    const u16* __restrict__ vth, const u16* __restrict__ vtl,
    u16* __restrict__ oh, u16* __restrict__ ol)
{
    flash_body<1>(qh, ql, vth, vtl, oh, ol, nullptr, nullptr, nullptr);
}

__global__ __launch_bounds__(256) void flash_attn_part2(
    const u16* __restrict__ qh, const u16* __restrict__ ql,
    const u16* __restrict__ vth, const u16* __restrict__ vtl,
    float* __restrict__ Opart, float* __restrict__ mpart,
    float* __restrict__ lpart)
{
    flash_body<2>(qh, ql, vth, vtl, nullptr, nullptr, Opart, mpart, lpart);
}

__global__ __launch_bounds__(256) void flash_attn_part4(
    const u16* __restrict__ qh, const u16* __restrict__ ql,
    const u16* __restrict__ vth, const u16* __restrict__ vtl,
    float* __restrict__ Opart, float* __restrict__ mpart,
    float* __restrict__ lpart)
{
    flash_body<4>(qh, ql, vth, vtl, nullptr, nullptr, Opart, mpart, lpart);
}

// Merge ns KV-split partials: out = sum(O_i*a_i) / sum(l_i*a_i),
// a_i = 2^(m_i - max_j m_j). Writes split bf16 pair. grid (SQ), 256 thr.
__global__ __launch_bounds__(256) void attn_combine(
    const float* __restrict__ Opart, const float* __restrict__ mpart,
    const float* __restrict__ lpart,
    u16* __restrict__ oh, u16* __restrict__ ol, int ns)
{
    const int row = blockIdx.x;
    const int tid = threadIdx.x;
#pragma unroll
    for (int i = 0; i < 2; i++) {
        int col = tid + i * 256;
        int h = col >> 6;   // HDIM=64
        float m = -1e30f;
        for (int zz = 0; zz < ns; zz++)
            m = fmaxf(m, mpart[(zz*NH + h) * SQ + row]);
        float O = 0.0f, l = 0.0f;
        for (int zz = 0; zz < ns; zz++) {
            float a = exp2f(mpart[(zz*NH + h) * SQ + row] - m);
            O += Opart[((size_t)zz * SQ + row) * DM + col] * a;
            l += lpart[(zz*NH + h) * SQ + row] * a;
        }
        float w = O / l;
        u16 hb = f2bf(w);
        oh[(size_t)row * DM + col] = hb;
        ol[(size_t)row * DM + col] = f2bf(w - bf2f(hb));
    }
}

// LN1: fp32 in -> split bf16 pair out.
__global__ __launch_bounds__(256) void ln1_split(
    const float* __restrict__ x, const float* __restrict__ g,
    const float* __restrict__ b, u16* __restrict__ ohi, u16* __restrict__ olo)
{
    const int row = blockIdx.x;
    const int tid = threadIdx.x;
    float v0 = x[(size_t)row * DM + tid];
    float v1 = x[(size_t)row * DM + tid + 256];
    float s = v0 + v1, sq = v0*v0 + v1*v1;
#pragma unroll
    for (int o = 1; o < 64; o <<= 1) { s += __shfl_xor(s, o); sq += __shfl_xor(sq, o); }
    __shared__ float ss[4], ssq[4];
    if ((tid & 63) == 0) { ss[tid>>6] = s; ssq[tid>>6] = sq; }
    __syncthreads();
    s  = ss[0]+ss[1]+ss[2]+ss[3];
    sq = ssq[0]+ssq[1]+ssq[2]+ssq[3];
    float m = s * (1.0f/DM);
    float rstd = rsqrtf(sq*(1.0f/DM) - m*m + 1e-5f);
    float y0 = (v0-m)*rstd*g[tid]     + b[tid];
    float y1 = (v1-m)*rstd*g[tid+256] + b[tid+256];
    u16 h0 = f2bf(y0), h1 = f2bf(y1);
    ohi[(size_t)row*DM + tid]       = h0;  olo[(size_t)row*DM + tid]       = f2bf(y0 - bf2f(h0));
    ohi[(size_t)row*DM + tid + 256] = h1;  olo[(size_t)row*DM + tid + 256] = f2bf(y1 - bf2f(h1));
}

// Coalesced V transpose via LDS 64x64 tiles (pad 66: both phases conflict-free)
__global__ __launch_bounds__(256) void transpose_v2(
    const u16* __restrict__ qh, const u16* __restrict__ ql,
    u16* __restrict__ vth, u16* __restrict__ vtl)
{
    __shared__ u16 Th[64 * 66], Tl[64 * 66];
    const int t0  = blockIdx.x * 64;
    const int hd0 = blockIdx.y * 64;
    const int tid = threadIdx.x;
#pragma unroll
    for (int k = 0; k < 16; k++) {
        int idx = tid + k * 256;
        int r = idx >> 6, j = idx & 63;      // r: token, j: dim (coalesced)
        size_t src = (size_t)(t0 + r) * (3*DM) + 2*DM + hd0 + j;
        Th[r * 66 + j] = qh[src];
        Tl[r * 66 + j] = ql[src];
    }
    __syncthreads();
#pragma unroll
    for (int k = 0; k < 16; k++) {
        int idx = tid + k * 256;
        int r = idx >> 6, c2 = idx & 63;     // r: dim, c2: token (coalesced)
        size_t dst = (size_t)(hd0 + r) * SQ + t0 + c2;
        vth[dst] = Th[c2 * 66 + r];
        vtl[dst] = Tl[c2 * 66 + r];
    }
}

// Gate (fp32 LN2) + top-2 compaction; writes bf16 LN2 output (xln2) AND the
// out = x1 residual copy (gate_route already reads all of x1).
__global__ __launch_bounds__(256) void gate_route(
    const float* __restrict__ x1, const float* __restrict__ g,
    const float* __restrict__ b, const float* __restrict__ gw,
    const float* __restrict__ gb,
    int* __restrict__ cnt, int* __restrict__ idxl, float* __restrict__ cw,
    u16* __restrict__ xout, float* __restrict__ outcpy)
{
    const int token = blockIdx.x * 4 + (threadIdx.x >> 6);
    const int lane  = threadIdx.x & 63;
    const float* xr = x1 + (size_t)token * DM;
    float v[8];
#pragma unroll
    for (int i = 0; i < 8; i++) v[i] = xr[lane*8 + i];
    // out = x1 copy (32B/lane contiguous)
    {
        float4* od = (float4*)(outcpy + (size_t)token * DM + lane*8);
        od[0] = make_float4(v[0], v[1], v[2], v[3]);
        od[1] = make_float4(v[4], v[5], v[6], v[7]);
    }
    float s = 0.f, sq = 0.f;
#pragma unroll
    for (int i = 0; i < 8; i++) { s += v[i]; sq += v[i]*v[i]; }
#pragma unroll
    for (int o = 1; o < 64; o <<= 1) { s += __shfl_xor(s, o); sq += __shfl_xor(sq, o); }
    float m = s * (1.0f/DM);
    float rstd = rsqrtf(sq*(1.0f/DM) - m*m + 1e-5f);
    float xn[8];
#pragma unroll
    for (int i = 0; i < 8; i++)
        xn[i] = (v[i]-m)*rstd*g[lane*8+i] + b[lane*8+i];
    // write bf16 LN2 output (coalesced 16B per lane)
    {
        uint4 w;
        w.x = (u32)f2bf(xn[0]) | ((u32)f2bf(xn[1]) << 16);
        w.y = (u32)f2bf(xn[2]) | ((u32)f2bf(xn[3]) << 16);
        w.z = (u32)f2bf(xn[4]) | ((u32)f2bf(xn[5]) << 16);
        w.w = (u32)f2bf(xn[6]) | ((u32)f2bf(xn[7]) << 16);
        *(uint4*)(xout + (size_t)token * DM + lane*8) = w;
    }
    float logit[8];
#pragma unroll
    for (int e = 0; e < 8; e++) {
        float t = 0.f;
#pragma unroll
        for (int i = 0; i < 8; i++) t += xn[i] * gw[e*DM + lane*8 + i];
#pragma unroll
        for (int o = 1; o < 64; o <<= 1) t += __shfl_xor(t, o);
        logit[e] = t + gb[e];
    }
    if (lane == 0) {
        float mx = -1e30f;
        for (int e = 0; e < 8; e++) mx = fmaxf(mx, logit[e]);
        float den = 0.f, p[8];
        for (int e = 0; e < 8; e++) { p[e] = __expf(logit[e] - mx); den += p[e]; }
        for (int e = 0; e < 8; e++) p[e] /= den;
        int i1 = 0;
        for (int e = 1; e < 8; e++) if (p[e] > p[i1]) i1 = e;
        int i2 = -1;
        for (int e = 0; e < 8; e++) { if (e == i1) continue; if (i2 < 0 || p[e] > p[i2]) i2 = e; }
        int s1 = atomicAdd(&cnt[i1], 1);
        idxl[i1*SQ + s1] = token;  cw[i1*SQ + s1] = p[i1];
        int s2 = atomicAdd(&cnt[i2], 1);
        idxl[i2*SQ + s2] = token;  cw[i2*SQ + s2] = p[i2];
    }
}

// fp32 weight -> split bf16 pair, TWO tensors (in_proj + out_proj) one launch
__global__ __launch_bounds__(256) void cvt_split_both(
    const float* __restrict__ wa, u16* __restrict__ wha, u16* __restrict__ wla,
    int na,
    const float* __restrict__ wb, u16* __restrict__ whb, u16* __restrict__ wlb,
    int nb)
{
    int i = blockIdx.x * 256 + threadIdx.x;
    const float* w; u16 *wh, *wl; int idx;
    if (i < na)           { w = wa; wh = wha; wl = wla; idx = i; }
    else if (i < na + nb) { w = wb; wh = whb; wl = wlb; idx = i - na; }
    else return;
    float v = w[idx];
    u16 h = f2bf(v);
    wh[idx] = h;
    wl[idx] = f2bf(v - bf2f(h));
}

__global__ __launch_bounds__(256) void sentinel_kernel(float* out, float v, int n)
{
    int i = blockIdx.x * 256 + threadIdx.x;
    if (i < n) out[i] = v;
}
__global__ __launch_bounds__(256) void scrub_kernel(float* out, int n)
{
    int i = blockIdx.x * 256 + threadIdx.x;
    if (i < n) { float v = out[i]; if (!isfinite(v)) out[i] = 777.0f; }
}

// ===========================================================================
extern "C" void kernel_launch(void* const* d_in, const int* in_sizes, int n_in,
                              void* d_out, int out_size, void* d_ws, size_t ws_size,
                              hipStream_t stream)
{
    const float* src        = (const float*)d_in[0];
    const float* in_proj_w  = (const float*)d_in[1];
    const float* in_proj_b  = (const float*)d_in[2];
    const float* out_proj_w = (const float*)d_in[3];
    const float* out_proj_b = (const float*)d_in[4];
    const float* ln1_g      = (const float*)d_in[5];
    const float* ln1_b      = (const float*)d_in[6];
    const float* ln2_g      = (const float*)d_in[7];
    const float* ln2_b      = (const float*)d_in[8];
    const float* gate_w     = (const float*)d_in[9];
    const float* gate_b     = (const float*)d_in[10];
    const float* w1         = (const float*)d_in[11];
    const float* b1         = (const float*)d_in[12];
    const float* w2         = (const float*)d_in[13];
    const float* b2         = (const float*)d_in[14];
    const float* wo         = (const float*)d_in[15];
    const float* bo         = (const float*)d_in[16];
    float* out = (float*)d_out;

    const size_t MB = (size_t)1 << 20;
    const size_t ROUTE = 512 * 1024;
    const size_t NEED      = ROUTE + 44 * MB;  // proven-fit base layout
    const size_t NEED_BIG2 = ROUTE + 61 * MB;  // + 16.5MB split-2 partials
    const size_t NEED_BIG4 = ROUTE + 78 * MB;  // + 33MB   split-4 partials
    if (ws_size < NEED) {
        sentinel_kernel<<<(SQ*DM)/256, 256, 0, stream>>>(out, 333.0f, SQ*DM);
        return;
    }
    int ns = 0;
    if (ws_size >= NEED_BIG4)      ns = 4;
    else if (ws_size >= NEED_BIG2) ns = 2;

    char* ws = (char*)d_ws;
    int*   cnt  = (int*)ws;                          // 8 ints
    int*   idxl = (int*)(ws + 1024);                 // 128 KiB
    float* cw   = (float*)(ws + 1024 + 128*1024);    // 128 KiB
    char*  base = ws + ROUTE;
    // phase-reused regions (MiB offsets from base):
    u16* xln1h = (u16*)(base);            // [0,4)   A  -> attnh (B)
    u16* xln1l = (u16*)(base + 4*MB);     // [4,8)   A  -> attnl (B)
    u16* attnh = (u16*)(base);
    u16* attnl = (u16*)(base + 4*MB);
    u16* qkvh  = (u16*)(base + 8*MB);     // [8,20)  A,B
    u16* qkvl  = (u16*)(base + 20*MB);    // [20,32) A,B
    float* x1  = (float*)(base + 8*MB);   // [8,16)  C (qkv dead after flash)
    u16* vth   = (u16*)(base + 32*MB);    // [32,36) A,B
    u16* vtl   = (u16*)(base + 36*MB);    // [36,40) A,B
    u16* xln2  = (u16*)(base + 36*MB);    // [36,40) C (vtl dead)
    u16* Hbuf  = (u16*)(base);            // [0,36)  D (9216 x 2048 bf16)
    u16* wph   = (u16*)(base + 40*MB);            // [40,41.5) in_proj hi
    u16* wpl   = (u16*)(base + 40*MB + 1536*1024);// [41.5,43) in_proj lo
    u16* woh   = (u16*)(base + 43*MB);            // [43,43.5) out_proj hi
    u16* wol   = (u16*)(base + 43*MB + 512*1024); // [43.5,44) out_proj lo
    // flash split partials: O fp32 at [44, 44+ns*8); m/l after
    float* Opart = (float*)(base + 44*MB);
    float* mpart;
    float* lpart;
    if (ns == 4) {
        mpart = (float*)(base + 76*MB);
        lpart = (float*)(base + 76*MB + 512*1024);
    } else {
        mpart = (float*)(base + 60*MB);
        lpart = (float*)(base + 60*MB + 256*1024);
    }
    // MoE bf16 weights (ns==4 tier only): overlay the DEAD partials region.
    u16* w1b = (u16*)(base + 44*MB);
    u16* w2b = (u16*)(base + 60*MB);
    u16* wob = (u16*)(base + 44*MB);

    // ---- weight prep (both proj weights, one launch) ----
    const int NA = 3*DM*DM, NB = DM*DM;
    cvt_split_both<<<(NA+NB)/256, 256, 0, stream>>>(
        in_proj_w, wph, wpl, NA, out_proj_w, woh, wol, NB);

    // ---- attention path (emulated fp32) ----
    ln1_split<<<SQ, 256, 0, stream>>>(src, ln1_g, ln1_b, xln1h, xln1l);
    gemm_split<<<dim3(32, 12), 256, 0, stream>>>(
        xln1h, xln1l, DM, wph, wpl, DM, SQ, 3*DM, DM,
        in_proj_b, nullptr, 0, qkvh, qkvl, nullptr, 3*DM, 0);
    transpose_v2<<<dim3(SQ/64, DM/64), 256, 0, stream>>>(qkvh, qkvl, vth, vtl);
    if (ns == 4) {
        flash_attn_part4<<<dim3(SQ/128, NH, 4), 256, 0, stream>>>(
            qkvh, qkvl, vth, vtl, Opart, mpart, lpart);
        attn_combine<<<SQ, 256, 0, stream>>>(Opart, mpart, lpart, attnh, attnl, 4);
    } else if (ns == 2) {
        flash_attn_part2<<<dim3(SQ/128, NH, 2), 256, 0, stream>>>(
            qkvh, qkvl, vth, vtl, Opart, mpart, lpart);
        attn_combine<<<SQ, 256, 0, stream>>>(Opart, mpart, lpart, attnh, attnl, 2);
    } else {
        flash_attn<<<dim3(SQ/128, NH), 256, 0, stream>>>(
            qkvh, qkvl, vth, vtl, attnh, attnl);
    }
    // x1 = src + bias (also zeroes cnt), then split-K=4 Wo accumulate
    init_x1<<<(SQ*DM/4)/256, 256, 0, stream>>>(src, out_proj_b, x1, cnt);
    gemm_split_ko<<<dim3(32, 4, 4), 256, 0, stream>>>(
        attnh, attnl, DM, woh, wol, DM, x1, DM);

    // ---- MoE (sparse top-2, all experts concurrent) ----
    gate_route<<<SQ/4, 256, 0, stream>>>(x1, ln2_g, ln2_b, gate_w, gate_b,
                                         cnt, idxl, cw, xln2, out);
    const int WN4 = (NE * FF * DM) / 4;   // 2,097,152 float4 per weight tensor
    if (ns == 4) {
        // partials region dead after attn_combine -> reuse for bf16 weights
        cvt_w_bf16_2<<<(2*WN4)/256, 256, 0, stream>>>(w1, w1b, w2, w2b, WN4);
        moe12_bf16<<<dim3(72, 16), 256, 0, stream>>>(       // H (overwrites [0,36M))
            xln2, DM, idxl, cnt, w1b, b1, w2b, b2, Hbuf);
        cvt_w_bf16<<<WN4/256, 256, 0, stream>>>(wo, wob, WN4);  // w1b dead
        moe_y_bf16<<<dim3(72, 4), 256, 0, stream>>>(
            Hbuf, wob, bo, idxl, cw, cnt, out);
    } else {
        moe12_all<<<dim3(72, 16), 256, 0, stream>>>(
            xln2, DM, idxl, cnt, w1, b1, w2, b2, Hbuf);
        moe_y_all<<<dim3(72, 4), 256, 0, stream>>>(
            Hbuf, wo, bo, idxl, cw, cnt, out);
    }

    scrub_kernel<<<(SQ*DM)/256, 256, 0, stream>>>(out, SQ*DM);
}

// Round 13
// 715.921 us; speedup vs baseline: 1.0122x; 1.0122x over previous
//
#include <hip/hip_runtime.h>
#include <hip/hip_bf16.h>
#include <math.h>

// S=4096, D=512, H=8, hd=64, F=2048, E=8, top-2. I/O fp32.
// Attention path: split-bf16 (hi+lo, 3-MFMA) emulated fp32 => fp32-faithful
// routing. MoE: sparse top-2, ALL experts in one launch, atomic fp32 scatter.
// R2: flash split-K over KV (partials + combine).
// R3: hw bf16 cvt, setprio (T5), defer-max (T13).
// R4: KP=64 + XOR 16B-granule swizzle.
// R5: in-loop reg staging (launch_bounds(256,N) caps VGPR -> spill trap).
// R6: MoE bf16 weights; split-K Wo.
// R7: swapped QK^T (S^T=mfma(K,Q)), LN2 fusion.
// R8 REVERTED: global_load_lds staging; moe_y split-K (4x atomics).
// R9: init_out folded into gate_route.
// R10: flash Q register-tiling: 32 Q rows/wave, K/V frags reused.
// R11: PV via v_mfma_f32_16x16x16_bf16: swapped-QK^T C-layout == K=16 A-frag
//      => zero cross-lane P movement. BEST MEASURED: 719.1us, flash 158,
//      MfmaUtil 42%.
// R12 (launch merging) measured neutral (+5.6us total; +5us on byte-identical
//      flash => cross-session noise ±5us dominates). R13: revert to exact R11
//      configuration to lock in the best-measured result. Remaining levers
//      (V-interleave, BK=64 MoE, 32x32 restructure) all have |EV| < noise.
#define SQ   4096
#define DM   512
#define NH   8
#define HDIM 64
#define FF   2048
#define NE   8

typedef unsigned short u16;
typedef unsigned int   u32;
typedef __attribute__((ext_vector_type(8))) __bf16 bf16x8;
typedef __attribute__((ext_vector_type(4))) __bf16 bf16x4;
typedef __attribute__((ext_vector_type(4))) float  f32x4;

__device__ __forceinline__ float bf2f(u16 v) {
    union { u32 i; float f; } c; c.i = ((u32)v) << 16; return c.f;
}
// RNE via hardware cvt (v_cvt_pk_bf16_f32; same tie-to-even as manual bits)
__device__ __forceinline__ u16 f2bf(float f) {
    union { __bf16 h; u16 u; } c; c.h = (__bf16)f; return c.u;
}

// K=16 MFMA via inline asm (instruction in gfx950 ISA; builtin name varies)
__device__ __forceinline__ void mfma16(f32x4 &c, bf16x4 a, bf16x4 b) {
    asm("v_mfma_f32_16x16x16_bf16 %0, %1, %2, %0" : "+v"(c) : "v"(a), "v"(b));
}

#define BM 128
#define BN 128
#define BK 32
#define BKP 40   // padded LDS row stride for GEMM kernels

// ===========================================================================
// Split-bf16 GEMM: C = (Ahi+Alo)@(Bhi+Blo)^T + bias. 3 MFMAs (hh+hl+lh).
// mode 0: split bf16 pair out. mode 1: fp32 out (+resid).
// ===========================================================================
__global__ __launch_bounds__(256) void gemm_split(
    const u16* __restrict__ Ahi, const u16* __restrict__ Alo, int lda,
    const u16* __restrict__ Bhi, const u16* __restrict__ Blo, int ldb,
    int M, int N, int K,
    const float* __restrict__ bias,
    const float* __restrict__ resid, int ldres,
    u16* __restrict__ Chi, u16* __restrict__ Clo,
    float* __restrict__ Cf, int ldc, int mode)
{
    __shared__ __align__(16) u16 Ash[BM * BKP], Asl[BM * BKP];
    __shared__ __align__(16) u16 Bsh[BN * BKP], Bsl[BN * BKP];
    const int tid  = threadIdx.x;
    const int wave = tid >> 6;
    const int lane = tid & 63;
    const int quad = lane >> 4;
    const int l16  = lane & 15;
    const int bm = blockIdx.x * BM;
    const int bn = blockIdx.y * BN;
    const int wm = (wave & 1) * 64;
    const int wn = (wave >> 1) * 64;

    f32x4 acc[4][4];
#pragma unroll
    for (int i = 0; i < 4; i++)
#pragma unroll
        for (int j = 0; j < 4; j++)
#pragma unroll
            for (int r = 0; r < 4; r++) acc[i][j][r] = 0.0f;

    for (int k0 = 0; k0 < K; k0 += BK) {
#pragma unroll
        for (int i = 0; i < 2; i++) {
            int c = tid + i * 256;
            int row = c >> 2;
            int col = (c & 3) << 3;
            int ga = bm + row, gb2 = bn + row;
            uint4 vah = make_uint4(0u,0u,0u,0u), val = vah, vbh = vah, vbl = vah;
            if (ga < M) {
                vah = *(const uint4*)(Ahi + (size_t)ga * lda + k0 + col);
                val = *(const uint4*)(Alo + (size_t)ga * lda + k0 + col);
            }
            if (gb2 < N) {
                vbh = *(const uint4*)(Bhi + (size_t)gb2 * ldb + k0 + col);
                vbl = *(const uint4*)(Blo + (size_t)gb2 * ldb + k0 + col);
            }
            *(uint4*)(Ash + row * BKP + col) = vah;
            *(uint4*)(Asl + row * BKP + col) = val;
            *(uint4*)(Bsh + row * BKP + col) = vbh;
            *(uint4*)(Bsl + row * BKP + col) = vbl;
        }
        __syncthreads();
        bf16x8 ah[4], al[4], bh[4], bl[4];
#pragma unroll
        for (int i = 0; i < 4; i++) {
            ah[i] = *(const bf16x8*)(Ash + (wm + i * 16 + l16) * BKP + quad * 8);
            al[i] = *(const bf16x8*)(Asl + (wm + i * 16 + l16) * BKP + quad * 8);
        }
#pragma unroll
        for (int j = 0; j < 4; j++) {
            bh[j] = *(const bf16x8*)(Bsh + (wn + j * 16 + l16) * BKP + quad * 8);
            bl[j] = *(const bf16x8*)(Bsl + (wn + j * 16 + l16) * BKP + quad * 8);
        }
#pragma unroll
        for (int i = 0; i < 4; i++)
#pragma unroll
            for (int j = 0; j < 4; j++) {
                acc[i][j] = __builtin_amdgcn_mfma_f32_16x16x32_bf16(ah[i], bh[j], acc[i][j], 0,0,0);
                acc[i][j] = __builtin_amdgcn_mfma_f32_16x16x32_bf16(ah[i], bl[j], acc[i][j], 0,0,0);
                acc[i][j] = __builtin_amdgcn_mfma_f32_16x16x32_bf16(al[i], bh[j], acc[i][j], 0,0,0);
            }
        __syncthreads();
    }

#pragma unroll
    for (int i = 0; i < 4; i++)
#pragma unroll
        for (int j = 0; j < 4; j++)
#pragma unroll
            for (int r = 0; r < 4; r++) {
                int row = bm + wm + i * 16 + quad * 4 + r;
                int col = bn + wn + j * 16 + l16;
                if (row >= M || col >= N) continue;
                float v = acc[i][j][r] + (bias ? bias[col] : 0.0f);
                size_t idx = (size_t)row * ldc + col;
                if (mode == 0) {
                    u16 hb = f2bf(v);
                    Chi[idx] = hb;
                    Clo[idx] = f2bf(v - bf2f(hb));
                } else {
                    if (resid) v += resid[(size_t)row * ldres + col];
                    Cf[idx] = v;
                }
            }
}

// ===========================================================================
// Split-K Wo projection: x1 += partial[(Ahi+Alo)@(Bhi+Blo)^T] over K-chunk z.
// grid (32, 4, 4). x1 must be pre-initialized with src + bias (init_x1).
// ===========================================================================
__global__ __launch_bounds__(256) void gemm_split_ko(
    const u16* __restrict__ Ahi, const u16* __restrict__ Alo, int lda,
    const u16* __restrict__ Bhi, const u16* __restrict__ Blo, int ldb,
    float* __restrict__ Cf, int ldc)
{
    __shared__ __align__(16) u16 Ash[BM * BKP], Asl[BM * BKP];
    __shared__ __align__(16) u16 Bsh[BN * BKP], Bsl[BN * BKP];
    const int tid  = threadIdx.x;
    const int wave = tid >> 6;
    const int lane = tid & 63;
    const int quad = lane >> 4;
    const int l16  = lane & 15;
    const int bm = blockIdx.x * BM;
    const int bn = blockIdx.y * BN;
    const int wm = (wave & 1) * 64;
    const int wn = (wave >> 1) * 64;
    const int KC    = DM / 4;              // 128 per z-chunk
    const int k0beg = blockIdx.z * KC;

    f32x4 acc[4][4];
#pragma unroll
    for (int i = 0; i < 4; i++)
#pragma unroll
        for (int j = 0; j < 4; j++)
#pragma unroll
            for (int r = 0; r < 4; r++) acc[i][j][r] = 0.0f;

    for (int k0 = k0beg; k0 < k0beg + KC; k0 += BK) {
#pragma unroll
        for (int i = 0; i < 2; i++) {
            int c = tid + i * 256;
            int row = c >> 2;
            int col = (c & 3) << 3;
            int ga = bm + row, gb2 = bn + row;
            uint4 vah = *(const uint4*)(Ahi + (size_t)ga * lda + k0 + col);
            uint4 val = *(const uint4*)(Alo + (size_t)ga * lda + k0 + col);
            uint4 vbh = *(const uint4*)(Bhi + (size_t)gb2 * ldb + k0 + col);
            uint4 vbl = *(const uint4*)(Blo + (size_t)gb2 * ldb + k0 + col);
            *(uint4*)(Ash + row * BKP + col) = vah;
            *(uint4*)(Asl + row * BKP + col) = val;
            *(uint4*)(Bsh + row * BKP + col) = vbh;
            *(uint4*)(Bsl + row * BKP + col) = vbl;
        }
        __syncthreads();
        bf16x8 ah[4], al[4], bh[4], bl[4];
#pragma unroll
        for (int i = 0; i < 4; i++) {
            ah[i] = *(const bf16x8*)(Ash + (wm + i * 16 + l16) * BKP + quad * 8);
            al[i] = *(const bf16x8*)(Asl + (wm + i * 16 + l16) * BKP + quad * 8);
        }
#pragma unroll
        for (int j = 0; j < 4; j++) {
            bh[j] = *(const bf16x8*)(Bsh + (wn + j * 16 + l16) * BKP + quad * 8);
            bl[j] = *(const bf16x8*)(Bsl + (wn + j * 16 + l16) * BKP + quad * 8);
        }
#pragma unroll
        for (int i = 0; i < 4; i++)
#pragma unroll
            for (int j = 0; j < 4; j++) {
                acc[i][j] = __builtin_amdgcn_mfma_f32_16x16x32_bf16(ah[i], bh[j], acc[i][j], 0,0,0);
                acc[i][j] = __builtin_amdgcn_mfma_f32_16x16x32_bf16(ah[i], bl[j], acc[i][j], 0,0,0);
                acc[i][j] = __builtin_amdgcn_mfma_f32_16x16x32_bf16(al[i], bh[j], acc[i][j], 0,0,0);
            }
        __syncthreads();
    }

#pragma unroll
    for (int i = 0; i < 4; i++)
#pragma unroll
        for (int j = 0; j < 4; j++)
#pragma unroll
            for (int r = 0; r < 4; r++) {
                int row = bm + wm + i * 16 + quad * 4 + r;
                int col = bn + wn + j * 16 + l16;
                atomicAdd(Cf + (size_t)row * ldc + col, acc[i][j][r]);
            }
}

// x1 = src + out_proj bias (broadcast over rows), float4 vectorized
__global__ __launch_bounds__(256) void init_x1(
    const float* __restrict__ src, const float* __restrict__ bias,
    float* __restrict__ x1)
{
    int i = blockIdx.x * 256 + threadIdx.x;      // float4 index
    int col4 = i & (DM / 4 - 1);
    float4 s = ((const float4*)src)[i];
    float4 b = ((const float4*)bias)[col4];
    s.x += b.x; s.y += b.y; s.z += b.z; s.w += b.w;
    ((float4*)x1)[i] = s;
}

// ===========================================================================
// MoE all-expert fused w1/w2 GEMM (fp32-weight fallback path)
// ===========================================================================
__global__ __launch_bounds__(256) void moe12_all(
    const u16* __restrict__ A, int lda,
    const int* __restrict__ idxl, const int* __restrict__ cnt,
    const int* __restrict__ off,
    const float* __restrict__ w1, const float* __restrict__ b1,
    const float* __restrict__ w2, const float* __restrict__ b2,
    u16* __restrict__ H)
{
    const int bmg = blockIdx.x * BM;
    if (bmg >= off[NE]) return;
    int e = 0;
    while (e < NE - 1 && bmg >= off[e + 1]) e++;
    const int M   = cnt[e];
    const int bml = bmg - off[e];
    if (bml >= M) return;
    const float* B1 = w1 + (size_t)e * FF * DM;
    const float* B2 = w2 + (size_t)e * FF * DM;
    const int*   rl = idxl + e * SQ;

    __shared__ __align__(16) u16 As[BM * BKP], Bs1[BN * BKP], Bs2[BN * BKP];
    const int tid  = threadIdx.x;
    const int wave = tid >> 6;
    const int lane = tid & 63;
    const int quad = lane >> 4;
    const int l16  = lane & 15;
    const int bn = blockIdx.y * BN;
    const int wm = (wave & 1) * 64;
    const int wn = (wave >> 1) * 64;

    f32x4 acc1[4][4], acc2[4][4];
#pragma unroll
    for (int i = 0; i < 4; i++)
#pragma unroll
        for (int j = 0; j < 4; j++)
#pragma unroll
            for (int r = 0; r < 4; r++) { acc1[i][j][r] = 0.0f; acc2[i][j][r] = 0.0f; }

    for (int k0 = 0; k0 < DM; k0 += BK) {
#pragma unroll
        for (int i = 0; i < 2; i++) {
            int c = tid + i * 256;
            int row = c >> 2;
            int col = (c & 3) << 3;
            uint4 va = make_uint4(0u,0u,0u,0u);
            int lr = bml + row;
            if (lr < M) {
                int ar = rl[lr];
                va = *(const uint4*)(A + (size_t)ar * lda + k0 + col);
            }
            *(uint4*)(As + row * BKP + col) = va;
        }
#pragma unroll
        for (int i = 0; i < 4; i++) {
            int c = tid + i * 256;
            int row = c >> 3;
            int col = (c & 7) << 2;
            float4 v1 = *(const float4*)(B1 + (size_t)(bn + row) * DM + k0 + col);
            float4 v2 = *(const float4*)(B2 + (size_t)(bn + row) * DM + k0 + col);
            ushort4 h1, h2;
            h1.x = f2bf(v1.x); h1.y = f2bf(v1.y); h1.z = f2bf(v1.z); h1.w = f2bf(v1.w);
            h2.x = f2bf(v2.x); h2.y = f2bf(v2.y); h2.z = f2bf(v2.z); h2.w = f2bf(v2.w);
            *(ushort4*)(Bs1 + row * BKP + col) = h1;
            *(ushort4*)(Bs2 + row * BKP + col) = h2;
        }
        __syncthreads();
        bf16x8 af[4], b1f[4], b2f[4];
#pragma unroll
        for (int i = 0; i < 4; i++)
            af[i] = *(const bf16x8*)(As + (wm + i * 16 + l16) * BKP + quad * 8);
#pragma unroll
        for (int j = 0; j < 4; j++) {
            b1f[j] = *(const bf16x8*)(Bs1 + (wn + j * 16 + l16) * BKP + quad * 8);
            b2f[j] = *(const bf16x8*)(Bs2 + (wn + j * 16 + l16) * BKP + quad * 8);
        }
#pragma unroll
        for (int i = 0; i < 4; i++)
#pragma unroll
            for (int j = 0; j < 4; j++) {
                acc1[i][j] = __builtin_amdgcn_mfma_f32_16x16x32_bf16(af[i], b1f[j], acc1[i][j], 0,0,0);
                acc2[i][j] = __builtin_amdgcn_mfma_f32_16x16x32_bf16(af[i], b2f[j], acc2[i][j], 0,0,0);
            }
        __syncthreads();
    }

#pragma unroll
    for (int i = 0; i < 4; i++)
#pragma unroll
        for (int j = 0; j < 4; j++)
#pragma unroll
            for (int r = 0; r < 4; r++) {
                int rowl = bml + wm + i * 16 + quad * 4 + r;
                if (rowl >= M) continue;
                int col = bn + wn + j * 16 + l16;
                float g1 = acc1[i][j][r] + b1[e * FF + col];
                float g2 = acc2[i][j][r] + b2[e * FF + col];
                float s  = g1 / (1.0f + __expf(-g1));
                H[(size_t)(off[e] + rowl) * FF + col] = f2bf(s * g2);
            }
}

// ===========================================================================
// MoE fused w1/w2 GEMM, pre-converted bf16 weights (identical numerics).
// ===========================================================================
__global__ __launch_bounds__(256) void moe12_bf16(
    const u16* __restrict__ A, int lda,
    const int* __restrict__ idxl, const int* __restrict__ cnt,
    const int* __restrict__ off,
    const u16* __restrict__ w1b, const float* __restrict__ b1,
    const u16* __restrict__ w2b, const float* __restrict__ b2,
    u16* __restrict__ H)
{
    const int bmg = blockIdx.x * BM;
    if (bmg >= off[NE]) return;
    int e = 0;
    while (e < NE - 1 && bmg >= off[e + 1]) e++;
    const int M   = cnt[e];
    const int bml = bmg - off[e];
    if (bml >= M) return;
    const u16* B1 = w1b + (size_t)e * FF * DM;
    const u16* B2 = w2b + (size_t)e * FF * DM;
    const int* rl = idxl + e * SQ;

    __shared__ __align__(16) u16 As[BM * BKP], Bs1[BN * BKP], Bs2[BN * BKP];
    const int tid  = threadIdx.x;
    const int wave = tid >> 6;
    const int lane = tid & 63;
    const int quad = lane >> 4;
    const int l16  = lane & 15;
    const int bn = blockIdx.y * BN;
    const int wm = (wave & 1) * 64;
    const int wn = (wave >> 1) * 64;

    f32x4 acc1[4][4], acc2[4][4];
#pragma unroll
    for (int i = 0; i < 4; i++)
#pragma unroll
        for (int j = 0; j < 4; j++)
#pragma unroll
            for (int r = 0; r < 4; r++) { acc1[i][j][r] = 0.0f; acc2[i][j][r] = 0.0f; }

    for (int k0 = 0; k0 < DM; k0 += BK) {
#pragma unroll
        for (int i = 0; i < 2; i++) {
            int c = tid + i * 256;
            int row = c >> 2;
            int col = (c & 3) << 3;
            uint4 va = make_uint4(0u,0u,0u,0u);
            int lr = bml + row;
            if (lr < M) {
                int ar = rl[lr];
                va = *(const uint4*)(A + (size_t)ar * lda + k0 + col);
            }
            *(uint4*)(As + row * BKP + col) = va;
            uint4 v1 = *(const uint4*)(B1 + (size_t)(bn + row) * DM + k0 + col);
            uint4 v2 = *(const uint4*)(B2 + (size_t)(bn + row) * DM + k0 + col);
            *(uint4*)(Bs1 + row * BKP + col) = v1;
            *(uint4*)(Bs2 + row * BKP + col) = v2;
        }
        __syncthreads();
        bf16x8 af[4], b1f[4], b2f[4];
#pragma unroll
        for (int i = 0; i < 4; i++)
            af[i] = *(const bf16x8*)(As + (wm + i * 16 + l16) * BKP + quad * 8);
#pragma unroll
        for (int j = 0; j < 4; j++) {
            b1f[j] = *(const bf16x8*)(Bs1 + (wn + j * 16 + l16) * BKP + quad * 8);
            b2f[j] = *(const bf16x8*)(Bs2 + (wn + j * 16 + l16) * BKP + quad * 8);
        }
#pragma unroll
        for (int i = 0; i < 4; i++)
#pragma unroll
            for (int j = 0; j < 4; j++) {
                acc1[i][j] = __builtin_amdgcn_mfma_f32_16x16x32_bf16(af[i], b1f[j], acc1[i][j], 0,0,0);
                acc2[i][j] = __builtin_amdgcn_mfma_f32_16x16x32_bf16(af[i], b2f[j], acc2[i][j], 0,0,0);
            }
        __syncthreads();
    }

#pragma unroll
    for (int i = 0; i < 4; i++)
#pragma unroll
        for (int j = 0; j < 4; j++)
#pragma unroll
            for (int r = 0; r < 4; r++) {
                int rowl = bml + wm + i * 16 + quad * 4 + r;
                if (rowl >= M) continue;
                int col = bn + wn + j * 16 + l16;
                float g1 = acc1[i][j][r] + b1[e * FF + col];
                float g2 = acc2[i][j][r] + b2[e * FF + col];
                float s  = g1 / (1.0f + __expf(-g1));
                H[(size_t)(off[e] + rowl) * FF + col] = f2bf(s * g2);
            }
}

// ===========================================================================
// MoE down-proj (fp32-weight fallback path), grid (72,4)
// ===========================================================================
__global__ __launch_bounds__(256) void moe_y_all(
    const u16* __restrict__ H,
    const float* __restrict__ wo, const float* __restrict__ bo,
    const int* __restrict__ idxl, const float* __restrict__ cw,
    const int* __restrict__ cnt, const int* __restrict__ off,
    float* __restrict__ out)
{
    const int bmg = blockIdx.x * BM;
    if (bmg >= off[NE]) return;
    int e = 0;
    while (e < NE - 1 && bmg >= off[e + 1]) e++;
    const int M   = cnt[e];
    const int bml = bmg - off[e];
    if (bml >= M) return;
    const float* B = wo + (size_t)e * DM * FF;

    __shared__ __align__(16) u16 As[BM * BKP], Bs[BN * BKP];
    const int tid  = threadIdx.x;
    const int wave = tid >> 6;
    const int lane = tid & 63;
    const int quad = lane >> 4;
    const int l16  = lane & 15;
    const int bn = blockIdx.y * BN;
    const int wm = (wave & 1) * 64;
    const int wn = (wave >> 1) * 64;

    f32x4 acc[4][4];
#pragma unroll
    for (int i = 0; i < 4; i++)
#pragma unroll
        for (int j = 0; j < 4; j++)
#pragma unroll
            for (int r = 0; r < 4; r++) acc[i][j][r] = 0.0f;

    for (int k0 = 0; k0 < FF; k0 += BK) {
#pragma unroll
        for (int i = 0; i < 2; i++) {
            int c = tid + i * 256;
            int row = c >> 2;
            int col = (c & 3) << 3;
            uint4 va = *(const uint4*)(H + (size_t)(bmg + row) * FF + k0 + col);
            *(uint4*)(As + row * BKP + col) = va;
        }
#pragma unroll
        for (int i = 0; i < 4; i++) {
            int c = tid + i * 256;
            int row = c >> 3;
            int col = (c & 7) << 2;
            float4 v = *(const float4*)(B + (size_t)(bn + row) * FF + k0 + col);
            ushort4 h;
            h.x = f2bf(v.x); h.y = f2bf(v.y); h.z = f2bf(v.z); h.w = f2bf(v.w);
            *(ushort4*)(Bs + row * BKP + col) = h;
        }
        __syncthreads();
        bf16x8 af[4], bf[4];
#pragma unroll
        for (int i = 0; i < 4; i++)
            af[i] = *(const bf16x8*)(As + (wm + i * 16 + l16) * BKP + quad * 8);
#pragma unroll
        for (int j = 0; j < 4; j++)
            bf[j] = *(const bf16x8*)(Bs + (wn + j * 16 + l16) * BKP + quad * 8);
#pragma unroll
        for (int i = 0; i < 4; i++)
#pragma unroll
            for (int j = 0; j < 4; j++)
                acc[i][j] = __builtin_amdgcn_mfma_f32_16x16x32_bf16(af[i], bf[j], acc[i][j], 0,0,0);
        __syncthreads();
    }

#pragma unroll
    for (int i = 0; i < 4; i++)
#pragma unroll
        for (int j = 0; j < 4; j++)
#pragma unroll
            for (int r = 0; r < 4; r++) {
                int rowl = bml + wm + i * 16 + quad * 4 + r;
                if (rowl >= M) continue;
                int col = bn + wn + j * 16 + l16;
                int tok = idxl[e * SQ + rowl];
                float wgt = cw[e * SQ + rowl];
                atomicAdd(out + (size_t)tok * DM + col,
                          wgt * (acc[i][j][r] + bo[e * DM + col]));
            }
}

// ===========================================================================
// MoE down-proj, pre-converted bf16 wo (identical numerics), grid (72,4)
// ===========================================================================
__global__ __launch_bounds__(256) void moe_y_bf16(
    const u16* __restrict__ H,
    const u16* __restrict__ wob, const float* __restrict__ bo,
    const int* __restrict__ idxl, const float* __restrict__ cw,
    const int* __restrict__ cnt, const int* __restrict__ off,
    float* __restrict__ out)
{
    const int bmg = blockIdx.x * BM;
    if (bmg >= off[NE]) return;
    int e = 0;
    while (e < NE - 1 && bmg >= off[e + 1]) e++;
    const int M   = cnt[e];
    const int bml = bmg - off[e];
    if (bml >= M) return;
    const u16* B = wob + (size_t)e * DM * FF;

    __shared__ __align__(16) u16 As[BM * BKP], Bs[BN * BKP];
    const int tid  = threadIdx.x;
    const int wave = tid >> 6;
    const int lane = tid & 63;
    const int quad = lane >> 4;
    const int l16  = lane & 15;
    const int bn = blockIdx.y * BN;
    const int wm = (wave & 1) * 64;
    const int wn = (wave >> 1) * 64;

    f32x4 acc[4][4];
#pragma unroll
    for (int i = 0; i < 4; i++)
#pragma unroll
        for (int j = 0; j < 4; j++)
#pragma unroll
            for (int r = 0; r < 4; r++) acc[i][j][r] = 0.0f;

    for (int k0 = 0; k0 < FF; k0 += BK) {
#pragma unroll
        for (int i = 0; i < 2; i++) {
            int c = tid + i * 256;
            int row = c >> 2;
            int col = (c & 3) << 3;
            uint4 va = *(const uint4*)(H + (size_t)(bmg + row) * FF + k0 + col);
            *(uint4*)(As + row * BKP + col) = va;
            uint4 vb = *(const uint4*)(B + (size_t)(bn + row) * FF + k0 + col);
            *(uint4*)(Bs + row * BKP + col) = vb;
        }
        __syncthreads();
        bf16x8 af[4], bf[4];
#pragma unroll
        for (int i = 0; i < 4; i++)
            af[i] = *(const bf16x8*)(As + (wm + i * 16 + l16) * BKP + quad * 8);
#pragma unroll
        for (int j = 0; j < 4; j++)
            bf[j] = *(const bf16x8*)(Bs + (wn + j * 16 + l16) * BKP + quad * 8);
#pragma unroll
        for (int i = 0; i < 4; i++)
#pragma unroll
            for (int j = 0; j < 4; j++)
                acc[i][j] = __builtin_amdgcn_mfma_f32_16x16x32_bf16(af[i], bf[j], acc[i][j], 0,0,0);
        __syncthreads();
    }

#pragma unroll
    for (int i = 0; i < 4; i++)
#pragma unroll
        for (int j = 0; j < 4; j++)
#pragma unroll
            for (int r = 0; r < 4; r++) {
                int rowl = bml + wm + i * 16 + quad * 4 + r;
                if (rowl >= M) continue;
                int col = bn + wn + j * 16 + l16;
                int tok = idxl[e * SQ + rowl];
                float wgt = cw[e * SQ + rowl];
                atomicAdd(out + (size_t)tok * DM + col,
                          wgt * (acc[i][j][r] + bo[e * DM + col]));
            }
}

// fp32 -> bf16 (RNE), float4/ushort4 vectorized
__global__ __launch_bounds__(256) void cvt_w_bf16(
    const float* __restrict__ w, u16* __restrict__ wb, int n4)
{
    int i = blockIdx.x * 256 + threadIdx.x;
    if (i < n4) {
        float4 v = ((const float4*)w)[i];
        ushort4 h;
        h.x = f2bf(v.x); h.y = f2bf(v.y); h.z = f2bf(v.z); h.w = f2bf(v.w);
        ((ushort4*)wb)[i] = h;
    }
}

// ===========================================================================
// Flash attention, split precision, SWAPPED QK^T (S^T = mfma(K, Q)).
// R10: each wave owns TWO 16-row Q blocks (qb=0,1); K/V frags reused.
// R11: PV via K=16 MFMAs (C-layout == A-frag layout; lane-local P).
// LDS: KP=64, XOR 16B-granule swizzle. SPLIT in {1,2,4} over KV.
// ===========================================================================
#define KP 64
#define SWZ(row, col) ((col) ^ (((row) & 7) << 3))   // u16 units, 16B granules
#define SCL 0.18033688011112042f   // 0.125 * log2(e)

// softmax + defer-max + bf16 split pack (lane-local, K=16 A-frags).
__device__ __forceinline__ void smax_pack(
    f32x4 (&s)[4], float &m_, float &l_, f32x4 (&o_)[4],
    bf16x4 (&pah)[4], bf16x4 (&pal)[4], int quad)
{
    // row max: local over 16 regs + 2 cross-quad shfl_xor
    float mx = s[0][0];
#pragma unroll
    for (int jn = 0; jn < 4; jn++)
#pragma unroll
        for (int r = 0; r < 4; r++) mx = fmaxf(mx, s[jn][r]);
    mx = fmaxf(mx, __shfl_xor(mx, 16));
    mx = fmaxf(mx, __shfl_xor(mx, 32));

    // defer-max (T13): only rescale when the max grew by >8 (p <= 2^8)
    int grew = (mx > m_ + 8.0f) ? 1 : 0;
    if (__any(grew)) {
        float nm  = fmaxf(m_, mx);
        float al2 = exp2f(m_ - nm);
        m_ = nm;
        l_ *= al2;
        float alq[4];
#pragma unroll
        for (int r = 0; r < 4; r++)
            alq[r] = __shfl(al2, quad*4 + r);   // al2 for q = quad*4+r
#pragma unroll
        for (int nd = 0; nd < 4; nd++)
#pragma unroll
            for (int r = 0; r < 4; r++) o_[nd][r] *= alq[r];
    }

    // p = exp2(s - m), row sum: local + 2 shfl_xor
    float rs = 0.0f;
#pragma unroll
    for (int jn = 0; jn < 4; jn++)
#pragma unroll
        for (int r = 0; r < 4; r++) {
            float p = exp2f(s[jn][r] - m_);
            s[jn][r] = p;
            rs += p;
        }
    rs += __shfl_xor(rs, 16);
    rs += __shfl_xor(rs, 32);
    l_ += rs;

    // pack hi/lo K=16 A-frags: reg j = P[q=l16][k=jn*16+quad*4+j] (lane-local)
#pragma unroll
    for (int jn = 0; jn < 4; jn++) {
        union { bf16x4 v; u16 u[4]; } hh, ll;
#pragma unroll
        for (int j = 0; j < 4; j++) {
            u16 hb = f2bf(s[jn][j]);
            hh.u[j] = hb;
            ll.u[j] = f2bf(s[jn][j] - bf2f(hb));
        }
        pah[jn] = hh.v;
        pal[jn] = ll.v;
    }
}

template <int SPLIT>
__device__ __forceinline__ void flash_body(
    const u16* __restrict__ qh, const u16* __restrict__ ql,
    const u16* __restrict__ vth, const u16* __restrict__ vtl,
    u16* __restrict__ oh, u16* __restrict__ ol,
    float* __restrict__ Opart, float* __restrict__ mpart,
    float* __restrict__ lpart)
{
    __shared__ __align__(16) u16 Ksh[64*KP], Ksl[64*KP], Vsh[64*KP], Vsl[64*KP];
    const int tid  = threadIdx.x;
    const int wave = tid >> 6;
    const int lane = tid & 63;
    const int quad = lane >> 4;
    const int l16  = lane & 15;
    const int h    = blockIdx.y;
    const int z    = (SPLIT > 1) ? blockIdx.z : 0;
    const int qbase = blockIdx.x * 128 + wave * 32;   // 32 Q rows per wave

    // staging geometry: thread covers rows (tid>>3) and (tid>>3)+32, 8 u16 cols
    const int r_st  = tid >> 3;                    // 0..31
    const int co_g  = (tid & 7) << 3;              // global col (u16)
    const int co_sw = SWZ(r_st, co_g);             // same for r_st+32 (&7 inv)

    // Q fragments for both 16-row blocks
    bf16x8 aqh0[2], aql0[2], aqh1[2], aql1[2];
#pragma unroll
    for (int kk = 0; kk < 2; kk++) {
        size_t off0 = (size_t)(qbase + l16) * (3*DM) + h*HDIM + kk*32 + quad*8;
        size_t off1 = off0 + (size_t)16 * (3*DM);
        aqh0[kk] = *(const bf16x8*)(qh + off0);
        aql0[kk] = *(const bf16x8*)(ql + off0);
        aqh1[kk] = *(const bf16x8*)(qh + off1);
        aql1[kk] = *(const bf16x8*)(ql + off1);
    }

    float m0 = -1e30f, l0 = 0.0f, m1 = -1e30f, l1 = 0.0f;
    f32x4 o0[4], o1[4];
#pragma unroll
    for (int nd = 0; nd < 4; nd++)
#pragma unroll
        for (int r = 0; r < 4; r++) { o0[nd][r] = 0.0f; o1[nd][r] = 0.0f; }

    const int NT    = SQ / 64 / SPLIT;
    const int jtBeg = z * NT, jtEnd = (z + 1) * NT;

    for (int jt = jtBeg; jt < jtEnd; jt++) {
        // stage K/V tile: global -> reg -> LDS (swizzled dest), in-loop
        {
            size_t koff0 = (size_t)(jt*64 + r_st) * (3*DM) + DM + h*HDIM + co_g;
            size_t voff0 = (size_t)(h*HDIM + r_st) * SQ + jt*64 + co_g;
            size_t koff1 = koff0 + (size_t)32 * (3*DM);
            size_t voff1 = voff0 + (size_t)32 * SQ;
            uint4 a0 = *(const uint4*)(qh  + koff0);
            uint4 a1 = *(const uint4*)(ql  + koff0);
            uint4 a2 = *(const uint4*)(vth + voff0);
            uint4 a3 = *(const uint4*)(vtl + voff0);
            uint4 b0 = *(const uint4*)(qh  + koff1);
            uint4 b1 = *(const uint4*)(ql  + koff1);
            uint4 b2 = *(const uint4*)(vth + voff1);
            uint4 b3 = *(const uint4*)(vtl + voff1);
            *(uint4*)(Ksh + r_st*KP + co_sw)      = a0;
            *(uint4*)(Ksl + r_st*KP + co_sw)      = a1;
            *(uint4*)(Vsh + r_st*KP + co_sw)      = a2;
            *(uint4*)(Vsl + r_st*KP + co_sw)      = a3;
            *(uint4*)(Ksh + (r_st+32)*KP + co_sw) = b0;
            *(uint4*)(Ksl + (r_st+32)*KP + co_sw) = b1;
            *(uint4*)(Vsh + (r_st+32)*KP + co_sw) = b2;
            *(uint4*)(Vsl + (r_st+32)*KP + co_sw) = b3;
        }
        __syncthreads();

        // QK^T swapped for both qb; K frags loaded ONCE, used 6x.
        f32x4 s0[4], s1[4];
        __builtin_amdgcn_s_setprio(1);
#pragma unroll
        for (int jn = 0; jn < 4; jn++) {
            f32x4 z0, z1;
#pragma unroll
            for (int r = 0; r < 4; r++) { z0[r] = 0.0f; z1[r] = 0.0f; }
#pragma unroll
            for (int kk = 0; kk < 2; kk++) {
                int krow = jn*16 + l16;
                int kcol = SWZ(krow, kk*32 + quad*8);
                bf16x8 kh = *(const bf16x8*)(Ksh + krow*KP + kcol);
                bf16x8 kl = *(const bf16x8*)(Ksl + krow*KP + kcol);
                z0 = __builtin_amdgcn_mfma_f32_16x16x32_bf16(kh, aqh0[kk], z0, 0,0,0);
                z0 = __builtin_amdgcn_mfma_f32_16x16x32_bf16(kl, aqh0[kk], z0, 0,0,0);
                z0 = __builtin_amdgcn_mfma_f32_16x16x32_bf16(kh, aql0[kk], z0, 0,0,0);
                z1 = __builtin_amdgcn_mfma_f32_16x16x32_bf16(kh, aqh1[kk], z1, 0,0,0);
                z1 = __builtin_amdgcn_mfma_f32_16x16x32_bf16(kl, aqh1[kk], z1, 0,0,0);
                z1 = __builtin_amdgcn_mfma_f32_16x16x32_bf16(kh, aql1[kk], z1, 0,0,0);
            }
#pragma unroll
            for (int r = 0; r < 4; r++) { z0[r] *= SCL; z1[r] *= SCL; }
            s0[jn] = z0;
            s1[jn] = z1;
        }
        __builtin_amdgcn_s_setprio(0);

        // softmax + lane-local pack per qb (no cross-lane redistribution)
        bf16x4 pah0[4], pal0[4], pah1[4], pal1[4];
        smax_pack(s0, m0, l0, o0, pah0, pal0, quad);
        smax_pack(s1, m1, l1, o1, pah1, pal1, quad);

        // PV via K=16 MFMAs; V b64 frags loaded ONCE, used 6x.
        __builtin_amdgcn_s_setprio(1);
#pragma unroll
        for (int nd = 0; nd < 4; nd++) {
            int vrow = nd*16 + l16;
#pragma unroll
            for (int jn = 0; jn < 4; jn++) {
                int vcol = SWZ(vrow, jn*16 + quad*4);
                bf16x4 vh = *(const bf16x4*)(Vsh + vrow*KP + vcol);
                bf16x4 vl = *(const bf16x4*)(Vsl + vrow*KP + vcol);
                mfma16(o0[nd], pah0[jn], vh);
                mfma16(o0[nd], pah0[jn], vl);
                mfma16(o0[nd], pal0[jn], vh);
                mfma16(o1[nd], pah1[jn], vh);
                mfma16(o1[nd], pah1[jn], vl);
                mfma16(o1[nd], pal1[jn], vh);
            }
        }
        __builtin_amdgcn_s_setprio(0);
        __syncthreads();   // before next tile overwrites Ks/Vs
    }

    if (SPLIT == 1) {
        float lq0[4], lq1[4];
#pragma unroll
        for (int r = 0; r < 4; r++) {
            lq0[r] = __shfl(l0, quad*4 + r);
            lq1[r] = __shfl(l1, quad*4 + r);
        }
#pragma unroll
        for (int nd = 0; nd < 4; nd++)
#pragma unroll
            for (int r = 0; r < 4; r++) {
                int row = qbase + quad*4 + r;
                int col = h*HDIM + nd*16 + l16;
                float w = o0[nd][r] / lq0[r];
                u16 hb = f2bf(w);
                oh[(size_t)row * DM + col] = hb;
                ol[(size_t)row * DM + col] = f2bf(w - bf2f(hb));
                int row1 = row + 16;
                float w1v = o1[nd][r] / lq1[r];
                u16 hb1 = f2bf(w1v);
                oh[(size_t)row1 * DM + col] = hb1;
                ol[(size_t)row1 * DM + col] = f2bf(w1v - bf2f(hb1));
            }
    } else {
        // unnormalized fp32 partials + per-row m/l (lanes 0..15 own q=l16)
#pragma unroll
        for (int nd = 0; nd < 4; nd++)
#pragma unroll
            for (int r = 0; r < 4; r++) {
                int row = qbase + quad*4 + r;
                int col = h*HDIM + nd*16 + l16;
                Opart[((size_t)z * SQ + row) * DM + col] = o0[nd][r];
                Opart[((size_t)z * SQ + row + 16) * DM + col] = o1[nd][r];
            }
        if (lane < 16) {
            int row = qbase + l16;
            mpart[(z*NH + h) * SQ + row] = m0;
            lpart[(z*NH + h) * SQ + row] = l0;
            mpart[(z*NH + h) * SQ + row + 16] = m1;
            lpart[(z*NH + h) * SQ + row + 16] = l1;
        }
    }
}

__global__ __launch_bounds__(256) void flash_attn(
    const u16* __restrict__ qh, const u16* __restrict__ ql,
    const u16* __restrict__ vth, const u16* __restrict__ vtl,
    u16* __restrict__ oh, u16* __restrict__ ol)
{
    flash_body<1>(qh, ql, vth, vtl, oh, ol, nullptr, nullptr, nullptr);
}

__global__ __launch_bounds__(256) void flash_attn_part2(
    const u16* __restrict__ qh, const u16* __restrict__ ql,
    const u16* __restrict__ vth, const u16* __restrict__ vtl,
    float* __restrict__ Opart, float* __restrict__ mpart,
    float* __restrict__ lpart)
{
    flash_body<2>(qh, ql, vth, vtl, nullptr, nullptr, Opart, mpart, lpart);
}

__global__ __launch_bounds__(256) void flash_attn_part4(
    const u16* __restrict__ qh, const u16* __restrict__ ql,
    const u16* __restrict__ vth, const u16* __restrict__ vtl,
    float* __restrict__ Opart, float* __restrict__ mpart,
    float* __restrict__ lpart)
{
    flash_body<4>(qh, ql, vth, vtl, nullptr, nullptr, Opart, mpart, lpart);
}

// Merge ns KV-split partials: out = sum(O_i*a_i) / sum(l_i*a_i),
// a_i = 2^(m_i - max_j m_j). Writes split bf16 pair. grid (SQ), 256 thr.
__global__ __launch_bounds__(256) void attn_combine(
    const float* __restrict__ Opart, const float* __restrict__ mpart,
    const float* __restrict__ lpart,
    u16* __restrict__ oh, u16* __restrict__ ol, int ns)
{
    const int row = blockIdx.x;
    const int tid = threadIdx.x;
#pragma unroll
    for (int i = 0; i < 2; i++) {
        int col = tid + i * 256;
        int h = col >> 6;   // HDIM=64
        float m = -1e30f;
        for (int zz = 0; zz < ns; zz++)
            m = fmaxf(m, mpart[(zz*NH + h) * SQ + row]);
        float O = 0.0f, l = 0.0f;
        for (int zz = 0; zz < ns; zz++) {
            float a = exp2f(mpart[(zz*NH + h) * SQ + row] - m);
            O += Opart[((size_t)zz * SQ + row) * DM + col] * a;
            l += lpart[(zz*NH + h) * SQ + row] * a;
        }
        float w = O / l;
        u16 hb = f2bf(w);
        oh[(size_t)row * DM + col] = hb;
        ol[(size_t)row * DM + col] = f2bf(w - bf2f(hb));
    }
}

// LN1: fp32 in -> split bf16 pair out.
__global__ __launch_bounds__(256) void ln1_split(
    const float* __restrict__ x, const float* __restrict__ g,
    const float* __restrict__ b, u16* __restrict__ ohi, u16* __restrict__ olo)
{
    const int row = blockIdx.x;
    const int tid = threadIdx.x;
    float v0 = x[(size_t)row * DM + tid];
    float v1 = x[(size_t)row * DM + tid + 256];
    float s = v0 + v1, sq = v0*v0 + v1*v1;
#pragma unroll
    for (int o = 1; o < 64; o <<= 1) { s += __shfl_xor(s, o); sq += __shfl_xor(sq, o); }
    __shared__ float ss[4], ssq[4];
    if ((tid & 63) == 0) { ss[tid>>6] = s; ssq[tid>>6] = sq; }
    __syncthreads();
    s  = ss[0]+ss[1]+ss[2]+ss[3];
    sq = ssq[0]+ssq[1]+ssq[2]+ssq[3];
    float m = s * (1.0f/DM);
    float rstd = rsqrtf(sq*(1.0f/DM) - m*m + 1e-5f);
    float y0 = (v0-m)*rstd*g[tid]     + b[tid];
    float y1 = (v1-m)*rstd*g[tid+256] + b[tid+256];
    u16 h0 = f2bf(y0), h1 = f2bf(y1);
    ohi[(size_t)row*DM + tid]       = h0;  olo[(size_t)row*DM + tid]       = f2bf(y0 - bf2f(h0));
    ohi[(size_t)row*DM + tid + 256] = h1;  olo[(size_t)row*DM + tid + 256] = f2bf(y1 - bf2f(h1));
}

// Coalesced V transpose via LDS 64x64 tiles (pad 66: both phases conflict-free)
__global__ __launch_bounds__(256) void transpose_v2(
    const u16* __restrict__ qh, const u16* __restrict__ ql,
    u16* __restrict__ vth, u16* __restrict__ vtl)
{
    __shared__ u16 Th[64 * 66], Tl[64 * 66];
    const int t0  = blockIdx.x * 64;
    const int hd0 = blockIdx.y * 64;
    const int tid = threadIdx.x;
#pragma unroll
    for (int k = 0; k < 16; k++) {
        int idx = tid + k * 256;
        int r = idx >> 6, j = idx & 63;      // r: token, j: dim (coalesced)
        size_t src = (size_t)(t0 + r) * (3*DM) + 2*DM + hd0 + j;
        Th[r * 66 + j] = qh[src];
        Tl[r * 66 + j] = ql[src];
    }
    __syncthreads();
#pragma unroll
    for (int k = 0; k < 16; k++) {
        int idx = tid + k * 256;
        int r = idx >> 6, c2 = idx & 63;     // r: dim, c2: token (coalesced)
        size_t dst = (size_t)(hd0 + r) * SQ + t0 + c2;
        vth[dst] = Th[c2 * 66 + r];
        vtl[dst] = Tl[c2 * 66 + r];
    }
}

// Gate (fp32 LN2) + top-2 compaction; writes bf16 LN2 output (xln2) AND the
// out = x1 residual copy (gate_route already reads all of x1).
__global__ __launch_bounds__(256) void gate_route(
    const float* __restrict__ x1, const float* __restrict__ g,
    const float* __restrict__ b, const float* __restrict__ gw,
    const float* __restrict__ gb,
    int* __restrict__ cnt, int* __restrict__ idxl, float* __restrict__ cw,
    u16* __restrict__ xout, float* __restrict__ outcpy)
{
    const int token = blockIdx.x * 4 + (threadIdx.x >> 6);
    const int lane  = threadIdx.x & 63;
    const float* xr = x1 + (size_t)token * DM;
    float v[8];
#pragma unroll
    for (int i = 0; i < 8; i++) v[i] = xr[lane*8 + i];
    // out = x1 copy (32B/lane contiguous)
    {
        float4* od = (float4*)(outcpy + (size_t)token * DM + lane*8);
        od[0] = make_float4(v[0], v[1], v[2], v[3]);
        od[1] = make_float4(v[4], v[5], v[6], v[7]);
    }
    float s = 0.f, sq = 0.f;
#pragma unroll
    for (int i = 0; i < 8; i++) { s += v[i]; sq += v[i]*v[i]; }
#pragma unroll
    for (int o = 1; o < 64; o <<= 1) { s += __shfl_xor(s, o); sq += __shfl_xor(sq, o); }
    float m = s * (1.0f/DM);
    float rstd = rsqrtf(sq*(1.0f/DM) - m*m + 1e-5f);
    float xn[8];
#pragma unroll
    for (int i = 0; i < 8; i++)
        xn[i] = (v[i]-m)*rstd*g[lane*8+i] + b[lane*8+i];
    // write bf16 LN2 output (coalesced 16B per lane)
    {
        uint4 w;
        w.x = (u32)f2bf(xn[0]) | ((u32)f2bf(xn[1]) << 16);
        w.y = (u32)f2bf(xn[2]) | ((u32)f2bf(xn[3]) << 16);
        w.z = (u32)f2bf(xn[4]) | ((u32)f2bf(xn[5]) << 16);
        w.w = (u32)f2bf(xn[6]) | ((u32)f2bf(xn[7]) << 16);
        *(uint4*)(xout + (size_t)token * DM + lane*8) = w;
    }
    float logit[8];
#pragma unroll
    for (int e = 0; e < 8; e++) {
        float t = 0.f;
#pragma unroll
        for (int i = 0; i < 8; i++) t += xn[i] * gw[e*DM + lane*8 + i];
#pragma unroll
        for (int o = 1; o < 64; o <<= 1) t += __shfl_xor(t, o);
        logit[e] = t + gb[e];
    }
    if (lane == 0) {
        float mx = -1e30f;
        for (int e = 0; e < 8; e++) mx = fmaxf(mx, logit[e]);
        float den = 0.f, p[8];
        for (int e = 0; e < 8; e++) { p[e] = __expf(logit[e] - mx); den += p[e]; }
        for (int e = 0; e < 8; e++) p[e] /= den;
        int i1 = 0;
        for (int e = 1; e < 8; e++) if (p[e] > p[i1]) i1 = e;
        int i2 = -1;
        for (int e = 0; e < 8; e++) { if (e == i1) continue; if (i2 < 0 || p[e] > p[i2]) i2 = e; }
        int s1 = atomicAdd(&cnt[i1], 1);
        idxl[i1*SQ + s1] = token;  cw[i1*SQ + s1] = p[i1];
        int s2 = atomicAdd(&cnt[i2], 1);
        idxl[i2*SQ + s2] = token;  cw[i2*SQ + s2] = p[i2];
    }
}

// fp32 weight -> split bf16 pair
__global__ __launch_bounds__(256) void cvt_split_w(
    const float* __restrict__ w, u16* __restrict__ wh, u16* __restrict__ wl, int n)
{
    int i = blockIdx.x * 256 + threadIdx.x;
    if (i < n) {
        float v = w[i];
        u16 h = f2bf(v);
        wh[i] = h;
        wl[i] = f2bf(v - bf2f(h));
    }
}

__global__ __launch_bounds__(64) void zero_cnt(int* cnt)
{
    if (threadIdx.x < NE) cnt[threadIdx.x] = 0;
}

// 128-aligned exclusive cumsum of cnt -> off[0..NE]
__global__ __launch_bounds__(64) void make_off(const int* __restrict__ cnt,
                                              int* __restrict__ off)
{
    if (threadIdx.x == 0) {
        int a = 0;
        for (int e = 0; e < NE; e++) {
            off[e] = a;
            a += ((cnt[e] + 127) >> 7) << 7;
        }
        off[NE] = a;
    }
}

__global__ __launch_bounds__(256) void sentinel_kernel(float* out, float v, int n)
{
    int i = blockIdx.x * 256 + threadIdx.x;
    if (i < n) out[i] = v;
}
__global__ __launch_bounds__(256) void scrub_kernel(float* out, int n)
{
    int i = blockIdx.x * 256 + threadIdx.x;
    if (i < n) { float v = out[i]; if (!isfinite(v)) out[i] = 777.0f; }
}

// ===========================================================================
extern "C" void kernel_launch(void* const* d_in, const int* in_sizes, int n_in,
                              void* d_out, int out_size, void* d_ws, size_t ws_size,
                              hipStream_t stream)
{
    const float* src        = (const float*)d_in[0];
    const float* in_proj_w  = (const float*)d_in[1];
    const float* in_proj_b  = (const float*)d_in[2];
    const float* out_proj_w = (const float*)d_in[3];
    const float* out_proj_b = (const float*)d_in[4];
    const float* ln1_g      = (const float*)d_in[5];
    const float* ln1_b      = (const float*)d_in[6];
    const float* ln2_g      = (const float*)d_in[7];
    const float* ln2_b      = (const float*)d_in[8];
    const float* gate_w     = (const float*)d_in[9];
    const float* gate_b     = (const float*)d_in[10];
    const float* w1         = (const float*)d_in[11];
    const float* b1         = (const float*)d_in[12];
    const float* w2         = (const float*)d_in[13];
    const float* b2         = (const float*)d_in[14];
    const float* wo         = (const float*)d_in[15];
    const float* bo         = (const float*)d_in[16];
    float* out = (float*)d_out;

    const size_t MB = (size_t)1 << 20;
    const size_t ROUTE = 512 * 1024;
    const size_t NEED      = ROUTE + 44 * MB;  // proven-fit base layout
    const size_t NEED_BIG2 = ROUTE + 61 * MB;  // + 16.5MB split-2 partials
    const size_t NEED_BIG4 = ROUTE + 78 * MB;  // + 33MB   split-4 partials
    if (ws_size < NEED) {
        sentinel_kernel<<<(SQ*DM)/256, 256, 0, stream>>>(out, 333.0f, SQ*DM);
        return;
    }
    int ns = 0;
    if (ws_size >= NEED_BIG4)      ns = 4;
    else if (ws_size >= NEED_BIG2) ns = 2;

    char* ws = (char*)d_ws;
    int*   cnt  = (int*)ws;                          // 8 ints
    int*   offp = (int*)(ws + 64);                   // 9 ints
    int*   idxl = (int*)(ws + 1024);                 // 128 KiB
    float* cw   = (float*)(ws + 1024 + 128*1024);    // 128 KiB
    char*  base = ws + ROUTE;
    // phase-reused regions (MiB offsets from base):
    u16* xln1h = (u16*)(base);            // [0,4)   A  -> attnh (B)
    u16* xln1l = (u16*)(base + 4*MB);     // [4,8)   A  -> attnl (B)
    u16* attnh = (u16*)(base);
    u16* attnl = (u16*)(base + 4*MB);
    u16* qkvh  = (u16*)(base + 8*MB);     // [8,20)  A,B
    u16* qkvl  = (u16*)(base + 20*MB);    // [20,32) A,B
    float* x1  = (float*)(base + 8*MB);   // [8,16)  C (qkv dead after flash)
    u16* vth   = (u16*)(base + 32*MB);    // [32,36) A,B
    u16* vtl   = (u16*)(base + 36*MB);    // [36,40) A,B
    u16* xln2  = (u16*)(base + 36*MB);    // [36,40) C (vtl dead)
    u16* Hbuf  = (u16*)(base);            // [0,36)  D (9216 x 2048 bf16)
    u16* wph   = (u16*)(base + 40*MB);            // [40,41.5) in_proj hi
    u16* wpl   = (u16*)(base + 40*MB + 1536*1024);// [41.5,43) in_proj lo
    u16* woh   = (u16*)(base + 43*MB);            // [43,43.5) out_proj hi
    u16* wol   = (u16*)(base + 43*MB + 512*1024); // [43.5,44) out_proj lo
    // flash split partials: O fp32 at [44, 44+ns*8); m/l after
    float* Opart = (float*)(base + 44*MB);
    float* mpart;
    float* lpart;
    if (ns == 4) {
        mpart = (float*)(base + 76*MB);
        lpart = (float*)(base + 76*MB + 512*1024);
    } else {
        mpart = (float*)(base + 60*MB);
        lpart = (float*)(base + 60*MB + 256*1024);
    }
    // MoE bf16 weights (ns==4 tier only): overlay the DEAD partials region.
    u16* w1b = (u16*)(base + 44*MB);
    u16* w2b = (u16*)(base + 60*MB);
    u16* wob = (u16*)(base + 44*MB);

    // ---- weight prep ----
    cvt_split_w<<<(3*DM*DM)/256, 256, 0, stream>>>(in_proj_w,  wph, wpl, 3*DM*DM);
    cvt_split_w<<<(DM*DM)/256,   256, 0, stream>>>(out_proj_w, woh, wol, DM*DM);

    // ---- attention path (emulated fp32) ----
    ln1_split<<<SQ, 256, 0, stream>>>(src, ln1_g, ln1_b, xln1h, xln1l);
    gemm_split<<<dim3(32, 12), 256, 0, stream>>>(
        xln1h, xln1l, DM, wph, wpl, DM, SQ, 3*DM, DM,
        in_proj_b, nullptr, 0, qkvh, qkvl, nullptr, 3*DM, 0);
    transpose_v2<<<dim3(SQ/64, DM/64), 256, 0, stream>>>(qkvh, qkvl, vth, vtl);
    if (ns == 4) {
        flash_attn_part4<<<dim3(SQ/128, NH, 4), 256, 0, stream>>>(
            qkvh, qkvl, vth, vtl, Opart, mpart, lpart);
        attn_combine<<<SQ, 256, 0, stream>>>(Opart, mpart, lpart, attnh, attnl, 4);
    } else if (ns == 2) {
        flash_attn_part2<<<dim3(SQ/128, NH, 2), 256, 0, stream>>>(
            qkvh, qkvl, vth, vtl, Opart, mpart, lpart);
        attn_combine<<<SQ, 256, 0, stream>>>(Opart, mpart, lpart, attnh, attnl, 2);
    } else {
        flash_attn<<<dim3(SQ/128, NH), 256, 0, stream>>>(
            qkvh, qkvl, vth, vtl, attnh, attnl);
    }
    // x1 = src + bias, then split-K=4 atomic accumulate of attn @ Wo^T
    init_x1<<<(SQ*DM/4)/256, 256, 0, stream>>>(src, out_proj_b, x1);
    gemm_split_ko<<<dim3(32, 4, 4), 256, 0, stream>>>(
        attnh, attnl, DM, woh, wol, DM, x1, DM);

    // ---- MoE (sparse top-2, all experts concurrent) ----
    zero_cnt<<<1, 64, 0, stream>>>(cnt);
    gate_route<<<SQ/4, 256, 0, stream>>>(x1, ln2_g, ln2_b, gate_w, gate_b,
                                         cnt, idxl, cw, xln2, out);
    make_off<<<1, 64, 0, stream>>>(cnt, offp);
    const int WN4 = (NE * FF * DM) / 4;   // 2,097,152 float4 per weight tensor
    if (ns == 4) {
        // partials region dead after attn_combine -> reuse for bf16 weights
        cvt_w_bf16<<<WN4/256, 256, 0, stream>>>(w1, w1b, WN4);
        cvt_w_bf16<<<WN4/256, 256, 0, stream>>>(w2, w2b, WN4);
        moe12_bf16<<<dim3(72, 16), 256, 0, stream>>>(       // H (overwrites [0,36M))
            xln2, DM, idxl, cnt, offp, w1b, b1, w2b, b2, Hbuf);
        cvt_w_bf16<<<WN4/256, 256, 0, stream>>>(wo, wob, WN4);  // w1b dead
        moe_y_bf16<<<dim3(72, 4), 256, 0, stream>>>(
            Hbuf, wob, bo, idxl, cw, cnt, offp, out);
    } else {
        moe12_all<<<dim3(72, 16), 256, 0, stream>>>(
            xln2, DM, idxl, cnt, offp, w1, b1, w2, b2, Hbuf);
        moe_y_all<<<dim3(72, 4), 256, 0, stream>>>(
            Hbuf, wo, bo, idxl, cw, cnt, offp, out);
    }

    scrub_kernel<<<(SQ*DM)/256, 256, 0, stream>>>(out, SQ*DM);
}